// Round 11
// baseline (859.310 us; speedup 1.0000x reference)
//
#include <hip/hip_runtime.h>
#include <hip/hip_bf16.h>

#define Bg 32
#define Nn 512
#define Fdim 6
#define Wd 128
#define KG 100
#define KP 3
#define DIM2 1536
#define GC16 16
#define NSL 12
#define KSL 128

typedef __hip_bfloat16 bf16;
typedef unsigned long long ull;

__device__ __forceinline__ float b2f(bf16 v) { return __bfloat162float(v); }
__device__ __forceinline__ float h2f(unsigned short h) { return __uint_as_float((unsigned)h << 16); }
__device__ __forceinline__ float lrelu(float v) { return v > 0.0f ? v : 0.01f * v; }

// ---------- dtype detection (f32=1 / bf16=0) ----------
__global__ void detect_kernel(const unsigned short* __restrict__ x, int* __restrict__ flag) {
  if (threadIdx.x == 0 && blockIdx.x == 0) {
    int big = 0;
    for (int i = 0; i < 512; i += 2) {
      unsigned short u = x[i];
      int e = (u >> 7) & 0xFF;
      if (e >= 140) big++;
    }
    *flag = (big > 20) ? 1 : 0;
  }
}

// ---------- convert x -> f32 ----------
__global__ void convert_kernel(const void* __restrict__ x, float* __restrict__ xf, int n,
                               const int* __restrict__ flag) {
  int i = blockIdx.x * 256 + threadIdx.x;
  if (i >= n) return;
  if (*flag) xf[i] = ((const float*)x)[i];
  else       xf[i] = b2f(((const bf16*)x)[i]);
}

// ---------- branchless sorted-3 insert ----------
__device__ __forceinline__ void ins3b(ull key, ull& k0, ull& k1, ull& k2) {
  ull M0 = k0 < key ? key : k0;  k0 = k0 < key ? k0 : key;
  ull M1 = k1 < M0 ? M0 : k1;    k1 = k1 < M0 ? k1 : M0;
  k2 = k2 < M1 ? k2 : M1;
}

// ---------- kNN k=100: one wave/row; ballot-popcount radix search ----------
__global__ void knn100_kernel(const float* __restrict__ xf, int* __restrict__ nbr) {
  __shared__ float xg[Nn * 7];
  __shared__ float sqv[Nn];
  int t = threadIdx.x; int w = t >> 6; int l = t & 63;
  int row0 = blockIdx.x * 4; int g = row0 >> 9;
  const float* xp = xf + g * (Nn * Fdim);
  for (int j = t; j < Nn; j += 256) {
    float s = 0.0f;
    #pragma unroll
    for (int c = 0; c < Fdim; c++) { float v = xp[j * Fdim + c]; xg[j * 7 + c] = v; s += v * v; }
    sqv[j] = s;
  }
  __syncthreads();
  int i = (row0 & 511) + w;
  float xi[Fdim];
  #pragma unroll
  for (int c = 0; c < Fdim; c++) xi[c] = xg[i * 7 + c];
  float sqi = sqv[i];
  unsigned m[8];
  #pragma unroll
  for (int ch = 0; ch < 8; ch++) {
    int j = ch * 64 + l;
    float dot = 0.0f;
    #pragma unroll
    for (int c = 0; c < Fdim; c++) dot += xi[c] * xg[j * 7 + c];
    float d = sqi + sqv[j] - 2.0f * dot;
    if (j == i) d += 1e10f;
    unsigned u = __float_as_uint(d);
    m[ch] = (u & 0x80000000u) ? ~u : (u | 0x80000000u);
  }
  unsigned T = 0u;
  for (int b = 31; b >= 0; b--) {
    unsigned mid = T | (1u << b);
    int c = 0;
    #pragma unroll
    for (int ch = 0; ch < 8; ch++) c += __popcll(__ballot(m[ch] < mid));
    if (c < KG) T = mid;
  }
  int* outp = nbr + ((size_t)(g * Nn + i)) * KG;
  ull lmask = (1ull << l) - 1ull;
  int base = 0;
  #pragma unroll
  for (int ch = 0; ch < 8; ch++) {
    bool less = m[ch] < T;
    ull bal = __ballot(less);
    if (less) outp[base + __popcll(bal & lmask)] = ch * 64 + l;
    base += __popcll(bal);
  }
  int need = KG - base;
  int eqb = 0;
  #pragma unroll
  for (int ch = 0; ch < 8; ch++) {
    bool eq = (m[ch] == T);
    ull bal = __ballot(eq);
    int gr = eqb + __popcll(bal & lmask);
    if (eq && gr < need) outp[base + gr] = ch * 64 + l;
    eqb += __popcll(bal);
  }
}

// ---------- kNN k=3 on coords: 16 lanes/row ----------
__global__ void knn3_x_kernel(const float* __restrict__ xf, int* __restrict__ nbr) {
  __shared__ float xg[Nn * 7];
  __shared__ float sqv[Nn];
  int t = threadIdx.x; int bid = blockIdx.x;
  int g = bid >> 5;
  const float* xp = xf + g * (Nn * Fdim);
  for (int j = t; j < Nn; j += 256) {
    float s = 0.0f;
    #pragma unroll
    for (int c = 0; c < Fdim; c++) { float v = xp[j * Fdim + c]; xg[j * 7 + c] = v; s += v * v; }
    sqv[j] = s;
  }
  __syncthreads();
  int lr = t >> 4; int sub = t & 15; int l = t & 63;
  int i = ((bid & 31) << 4) + lr;
  float xi[Fdim];
  #pragma unroll
  for (int c = 0; c < Fdim; c++) xi[c] = xg[i * 7 + c];
  float sqi = sqv[i];
  ull k0 = ~0ull, k1 = ~0ull, k2 = ~0ull;
  for (int jj = 0; jj < 32; jj++) {
    int s = (jj + l) & 31;
    int j = sub * 32 + s;
    float dot = 0.0f;
    #pragma unroll
    for (int c = 0; c < Fdim; c++) dot += xi[c] * xg[j * 7 + c];
    float d = sqi + sqv[j] - 2.0f * dot;
    if (j == i) d += 1e10f;
    unsigned u = __float_as_uint(d);
    unsigned m = (u & 0x80000000u) ? ~u : (u | 0x80000000u);
    ins3b(((ull)m << 32) | (unsigned)j, k0, k1, k2);
  }
  #pragma unroll
  for (int off = 1; off <= 8; off <<= 1) {
    ull b0 = __shfl_xor(k0, off, 64);
    ull b1 = __shfl_xor(k1, off, 64);
    ull b2 = __shfl_xor(k2, off, 64);
    ins3b(b0, k0, k1, k2); ins3b(b1, k0, k1, k2); ins3b(b2, k0, k1, k2);
  }
  if (sub == 0) {
    int row = g * Nn + i;
    nbr[row * 3 + 0] = (int)(k0 & 0xFFFFFFFFu);
    nbr[row * 3 + 1] = (int)(k1 & 0xFFFFFFFFu);
    nbr[row * 3 + 2] = (int)(k2 & 0xFFFFFFFFu);
  }
}

// ---------- kNN k=3 from chunked Gram ----------
__global__ void knn3_gram_kernel(const float* __restrict__ G, int* __restrict__ nbr, int g0) {
  __shared__ float sqv[Nn];
  int t = threadIdx.x; int bid = blockIdx.x;
  int gl = bid >> 5; int g = g0 + gl;
  const float* Gg = G + (size_t)gl * Nn * Nn;
  for (int j = t; j < Nn; j += 256) sqv[j] = Gg[(size_t)j * Nn + j];
  __syncthreads();
  int lr = t >> 4; int sub = t & 15; int l = t & 63;
  int i = ((bid & 31) << 4) + lr;
  float sqi = sqv[i];
  const float* Gr = Gg + (size_t)i * Nn;
  ull k0 = ~0ull, k1 = ~0ull, k2 = ~0ull;
  for (int jj = 0; jj < 32; jj++) {
    int s = (jj + l) & 31;
    int j = sub * 32 + s;
    float d = sqi + sqv[j] - 2.0f * Gr[j];
    if (j == i) d += 1e10f;
    unsigned u = __float_as_uint(d);
    unsigned m = (u & 0x80000000u) ? ~u : (u | 0x80000000u);
    ins3b(((ull)m << 32) | (unsigned)j, k0, k1, k2);
  }
  #pragma unroll
  for (int off = 1; off <= 8; off <<= 1) {
    ull b0 = __shfl_xor(k0, off, 64);
    ull b1 = __shfl_xor(k1, off, 64);
    ull b2 = __shfl_xor(k2, off, 64);
    ins3b(b0, k0, k1, k2); ins3b(b1, k0, k1, k2); ins3b(b2, k0, k1, k2);
  }
  if (sub == 0) {
    int row = g * Nn + i;
    nbr[row * 3 + 0] = (int)(k0 & 0xFFFFFFFFu);
    nbr[row * 3 + 1] = (int)(k1 & 0xFFFFFFFFu);
    nbr[row * 3 + 2] = (int)(k2 & 0xFFFFFFFFu);
  }
}

// ---------- neighbor-mean over 100, C=6 ----------
__global__ void gm6_kernel(const float* __restrict__ src, const int* __restrict__ nbr,
                           float* __restrict__ dst) {
  __shared__ float s[Nn * Fdim];
  int g = blockIdx.x; int t = threadIdx.x;  // 512
  const float* sp = src + g * (Nn * Fdim);
  for (int idx = t; idx < Nn * Fdim; idx += 512) s[idx] = sp[idx];
  __syncthreads();
  float acc[Fdim] = {0, 0, 0, 0, 0, 0};
  const int* nb = nbr + ((size_t)(g * Nn + t)) * KG;
  for (int k = 0; k < KG; k++) {
    int j = nb[k];
    #pragma unroll
    for (int c = 0; c < Fdim; c++) acc[c] += s[j * Fdim + c];
  }
  float* dp = dst + (size_t)(g * Nn + t) * Fdim;
  #pragma unroll
  for (int c = 0; c < Fdim; c++) dp[c] = acc[c] / 100.0f;
}

// ---------- neighbor-mean over 100, C=128: 8 rows/block, float4 gathers ----------
__global__ void gm128_kernel(const float* __restrict__ src, const int* __restrict__ nbr,
                             float* __restrict__ dst) {
  __shared__ int ids[8][KG];
  int t = threadIdx.x;  // 256
  int row0 = blockIdx.x * 8; int g = row0 >> 9;
  for (int idx = t; idx < 8 * KG; idx += 256) {
    int r = idx / KG, k = idx - r * KG;
    ids[r][k] = nbr[(size_t)(row0 + r) * KG + k];
  }
  __syncthreads();
  int lane = t & 31, r = t >> 5;  // r in 0..7
  const float4* sp = (const float4*)(src + (size_t)g * Nn * Wd);
  float ax = 0.0f, ay = 0.0f, az = 0.0f, aw = 0.0f;
  #pragma unroll 5
  for (int k = 0; k < KG; k++) {
    float4 v = sp[ids[r][k] * 32 + lane];
    ax += v.x; ay += v.y; az += v.z; aw += v.w;
  }
  float4 o = make_float4(ax / 100.0f, ay / 100.0f, az / 100.0f, aw / 100.0f);
  ((float4*)(dst + (size_t)(row0 + r) * Wd))[lane] = o;
}

// ---------- proj3 small (C=6 only; proven r10 path) ----------
__global__ void proj3_kernel(const float* __restrict__ in0, const float* __restrict__ in1,
                             const float* __restrict__ in2, const void* __restrict__ Wt_,
                             const void* __restrict__ bt_, float* __restrict__ out,
                             const int* __restrict__ flag) {
  __shared__ float s0[48], s1[48], s2[48];
  int t = threadIdx.x;  // 128
  int node0 = blockIdx.x * 8;
  int f32 = *flag;
  float acc[8] = {0, 0, 0, 0, 0, 0, 0, 0};
  float bd;
  if (t < 48) {
    s0[t] = in0[(size_t)node0 * 6 + t];
    s1[t] = in1[(size_t)node0 * 6 + t];
    s2[t] = in2[(size_t)node0 * 6 + t];
  }
  __syncthreads();
  if (f32) {
    const float* W = (const float*)Wt_;
    for (int c = 0; c < 6; c++) {
      float w0 = W[c * 128 + t], w1 = W[(6 + c) * 128 + t], w2 = W[(12 + c) * 128 + t];
      #pragma unroll
      for (int n = 0; n < 8; n++)
        acc[n] += s0[n * 6 + c] * w0 + s1[n * 6 + c] * w1 + s2[n * 6 + c] * w2;
    }
    bd = ((const float*)bt_)[t];
  } else {
    const bf16* W = (const bf16*)Wt_;
    for (int c = 0; c < 6; c++) {
      float w0 = b2f(W[c * 128 + t]), w1 = b2f(W[(6 + c) * 128 + t]), w2 = b2f(W[(12 + c) * 128 + t]);
      #pragma unroll
      for (int n = 0; n < 8; n++)
        acc[n] += s0[n * 6 + c] * w0 + s1[n * 6 + c] * w1 + s2[n * 6 + c] * w2;
    }
    bd = b2f(((const bf16*)bt_)[t]);
  }
  #pragma unroll
  for (int n = 0; n < 8; n++)
    out[(size_t)(node0 + n) * 128 + t] = lrelu(acc[n] + bd);
}

// ---------- proj3 big (C=128): chunk-staged W in LDS (64 rows, single-buffered) ----------
__global__ void proj3_big_kernel(const float* __restrict__ in0, const float* __restrict__ in1,
                                 const float* __restrict__ in2, const void* __restrict__ Wt_,
                                 const void* __restrict__ bt_, float* __restrict__ out,
                                 long Woff, long boff, const int* __restrict__ flag) {
  __shared__ __align__(16) float sa[3][32 * 128];  // 48 KB
  __shared__ __align__(16) float Wc[64 * 128];     // 32 KB chunk
  int t = threadIdx.x;  // 256
  int node0 = blockIdx.x * 32;
  int f32 = *flag;
  // ---- stage inputs ----
  {
    const float4* q0 = (const float4*)(in0 + (size_t)node0 * 128);
    const float4* q1 = (const float4*)(in1 + (size_t)node0 * 128);
    const float4* q2 = (const float4*)(in2 + (size_t)node0 * 128);
    float4* s0 = (float4*)sa[0]; float4* s1 = (float4*)sa[1]; float4* s2 = (float4*)sa[2];
    #pragma unroll
    for (int it = 0; it < 4; it++) {
      s0[t + it * 256] = q0[t + it * 256];
      s1[t + it * 256] = q1[t + it * 256];
      s2[t + it * 256] = q2[t + it * 256];
    }
  }
  int tx = t & 31, ty = t >> 5;
  int col0 = tx * 4, n0 = ty * 4;
  float acc[4][4];
  #pragma unroll
  for (int n = 0; n < 4; n++)
    #pragma unroll
    for (int j = 0; j < 4; j++) acc[n][j] = 0.0f;
  for (int half = 0; half < 6; half++) {   // a = half>>1, 64-row half h = half&1
    int a = half >> 1, h = half & 1;
    {
      float4* Wl = (float4*)Wc;
      if (f32) {
        const float4* Wg = (const float4*)((const float*)Wt_ + Woff
                                           + (size_t)a * 16384 + (size_t)h * 8192);
        #pragma unroll
        for (int i = 0; i < 8; i++) Wl[t + i * 256] = Wg[t + i * 256];
      } else {
        const ushort4* Wg = (const ushort4*)((const unsigned short*)Wt_ + Woff
                                             + (size_t)a * 16384 + (size_t)h * 8192);
        #pragma unroll
        for (int i = 0; i < 8; i++) {
          ushort4 hh = Wg[t + i * 256];
          Wl[t + i * 256] = make_float4(h2f(hh.x), h2f(hh.y), h2f(hh.z), h2f(hh.w));
        }
      }
    }
    __syncthreads();   // chunk (and, on half=0, inputs) visible
    const float* sp = sa[a];
    int cbase = h * 64;
    #pragma unroll 4
    for (int cc0 = 0; cc0 < 64; cc0 += 4) {
      float wv[4][4];
      #pragma unroll
      for (int cc = 0; cc < 4; cc++) {
        float4 w4 = *(const float4*)&Wc[(cc0 + cc) * 128 + col0];
        wv[cc][0] = w4.x; wv[cc][1] = w4.y; wv[cc][2] = w4.z; wv[cc][3] = w4.w;
      }
      int c0 = cbase + cc0;
      #pragma unroll
      for (int n = 0; n < 4; n++) {
        float4 av = *(const float4*)&sp[(n0 + n) * 128 + c0];
        #pragma unroll
        for (int j = 0; j < 4; j++)
          acc[n][j] += av.x * wv[0][j] + av.y * wv[1][j] + av.z * wv[2][j] + av.w * wv[3][j];
      }
    }
    __syncthreads();   // protect Wc before next stage
  }
  float bdv[4];
  if (f32) {
    const float* bt = (const float*)bt_ + boff;
    #pragma unroll
    for (int j = 0; j < 4; j++) bdv[j] = bt[col0 + j];
  } else {
    const bf16* bt = (const bf16*)bt_ + boff;
    #pragma unroll
    for (int j = 0; j < 4; j++) bdv[j] = b2f(bt[col0 + j]);
  }
  #pragma unroll
  for (int n = 0; n < 4; n++) {
    float4 ov;
    ov.x = lrelu(acc[n][0] + bdv[0]); ov.y = lrelu(acc[n][1] + bdv[1]);
    ov.z = lrelu(acc[n][2] + bdv[2]); ov.w = lrelu(acc[n][3] + bdv[3]);
    *(float4*)&out[(size_t)(node0 + n0 + n) * 128 + col0] = ov;
  }
}

// ---------- proj_dual small (C=6 only; proven r10 path) ----------
__global__ void proj_dual_kernel(const float* __restrict__ in, const void* __restrict__ Wt_,
                                 float* __restrict__ u, float* __restrict__ v,
                                 const int* __restrict__ flag) {
  __shared__ float s0[48];
  int t = threadIdx.x; int node0 = blockIdx.x * 8;
  int f32 = *flag;
  float au[8] = {0, 0, 0, 0, 0, 0, 0, 0};
  float av[8] = {0, 0, 0, 0, 0, 0, 0, 0};
  if (t < 48) s0[t] = in[(size_t)node0 * 6 + t];
  __syncthreads();
  if (f32) {
    const float* W = (const float*)Wt_;
    for (int c = 0; c < 6; c++) {
      float wa = W[c * 128 + t], wb = W[(6 + c) * 128 + t];
      #pragma unroll
      for (int n = 0; n < 8; n++) { float x = s0[n * 6 + c]; au[n] += x * wa; av[n] += x * wb; }
    }
  } else {
    const bf16* W = (const bf16*)Wt_;
    for (int c = 0; c < 6; c++) {
      float wa = b2f(W[c * 128 + t]), wb = b2f(W[(6 + c) * 128 + t]);
      #pragma unroll
      for (int n = 0; n < 8; n++) { float x = s0[n * 6 + c]; au[n] += x * wa; av[n] += x * wb; }
    }
  }
  #pragma unroll
  for (int n = 0; n < 8; n++) {
    u[(size_t)(node0 + n) * 128 + t] = au[n];
    v[(size_t)(node0 + n) * 128 + t] = av[n];
  }
}

// ---------- proj_dual big (C=128): chunk-staged W in LDS (4 x 64-row chunks) ----------
__global__ void proj_dual_big_kernel(const float* __restrict__ in, const void* __restrict__ Wt_,
                                     float* __restrict__ u, float* __restrict__ v,
                                     long Woff, const int* __restrict__ flag) {
  __shared__ __align__(16) float sa[32 * 128];     // 16 KB
  __shared__ __align__(16) float Wc[64 * 128];     // 32 KB chunk
  int t = threadIdx.x;  // 256
  int node0 = blockIdx.x * 32;
  int f32 = *flag;
  {
    const float4* qp = (const float4*)(in + (size_t)node0 * 128);
    float4* s0 = (float4*)sa;
    #pragma unroll
    for (int it = 0; it < 4; it++) s0[t + it * 256] = qp[t + it * 256];
  }
  int tx = t & 31, ty = t >> 5;
  int col0 = tx * 4, n0 = ty * 4;
  float accu[4][4], accv[4][4];
  #pragma unroll
  for (int n = 0; n < 4; n++)
    #pragma unroll
    for (int j = 0; j < 4; j++) { accu[n][j] = 0.0f; accv[n][j] = 0.0f; }
  for (int q = 0; q < 4; q++) {
    {
      float4* Wl = (float4*)Wc;
      if (f32) {
        const float4* Wg = (const float4*)((const float*)Wt_ + Woff + (size_t)q * 8192);
        #pragma unroll
        for (int i = 0; i < 8; i++) Wl[t + i * 256] = Wg[t + i * 256];
      } else {
        const ushort4* Wg = (const ushort4*)((const unsigned short*)Wt_ + Woff
                                             + (size_t)q * 8192);
        #pragma unroll
        for (int i = 0; i < 8; i++) {
          ushort4 hh = Wg[t + i * 256];
          Wl[t + i * 256] = make_float4(h2f(hh.x), h2f(hh.y), h2f(hh.z), h2f(hh.w));
        }
      }
    }
    __syncthreads();
    int cbase = (q & 1) * 64;
    if (q < 2) {
      #pragma unroll 4
      for (int cc0 = 0; cc0 < 64; cc0 += 4) {
        float wv[4][4];
        #pragma unroll
        for (int cc = 0; cc < 4; cc++) {
          float4 w4 = *(const float4*)&Wc[(cc0 + cc) * 128 + col0];
          wv[cc][0] = w4.x; wv[cc][1] = w4.y; wv[cc][2] = w4.z; wv[cc][3] = w4.w;
        }
        int c0 = cbase + cc0;
        #pragma unroll
        for (int n = 0; n < 4; n++) {
          float4 av = *(const float4*)&sa[(n0 + n) * 128 + c0];
          #pragma unroll
          for (int j = 0; j < 4; j++)
            accu[n][j] += av.x * wv[0][j] + av.y * wv[1][j] + av.z * wv[2][j] + av.w * wv[3][j];
        }
      }
    } else {
      #pragma unroll 4
      for (int cc0 = 0; cc0 < 64; cc0 += 4) {
        float wv[4][4];
        #pragma unroll
        for (int cc = 0; cc < 4; cc++) {
          float4 w4 = *(const float4*)&Wc[(cc0 + cc) * 128 + col0];
          wv[cc][0] = w4.x; wv[cc][1] = w4.y; wv[cc][2] = w4.z; wv[cc][3] = w4.w;
        }
        int c0 = cbase + cc0;
        #pragma unroll
        for (int n = 0; n < 4; n++) {
          float4 av = *(const float4*)&sa[(n0 + n) * 128 + c0];
          #pragma unroll
          for (int j = 0; j < 4; j++)
            accv[n][j] += av.x * wv[0][j] + av.y * wv[1][j] + av.z * wv[2][j] + av.w * wv[3][j];
        }
      }
    }
    __syncthreads();
  }
  #pragma unroll
  for (int n = 0; n < 4; n++) {
    *(float4*)&u[(size_t)(node0 + n0 + n) * 128 + col0] = *(float4*)accu[n];
    *(float4*)&v[(size_t)(node0 + n0 + n) * 128 + col0] = *(float4*)accv[n];
  }
}

// ---------- edgeconv1: 32 nodes/block, 6x8 tile, XOR-swizzled tl + split cols ----------
// r9 post-mortem: 6x8 tile caused (a) 4-way bank conflict on tl reads (4 wave-
// concurrent rows at 3072 B stride = same bank-quad; 3.67M conflicts) and
// (b) partial-line y stores (cols tx*8 -> 32 B-stride 16 B stores; WRITE 2x).
// r10 fix: (a) tl XOR-swizzle col ^= (row&7)<<2 -> concurrent rows hit distinct
// bank-quads (G4); (b) thread owns cols [tx*4, +3] and [64+tx*4, +3] -> every
// W-read / y-store instruction is 16 lanes x 16 B contiguous.
#define TLS(row, col) ((row) * 128 + ((col) ^ (((row) & 7) << 2)))
__global__ void edge_mlp1_kernel(const float* __restrict__ u, const float* __restrict__ v,
                                 const int* __restrict__ nbrp, const void* __restrict__ W2_,
                                 const void* __restrict__ b1_, const void* __restrict__ b2_,
                                 float* __restrict__ y, const int* __restrict__ flag) {
  __shared__ __align__(16) float Ws[64 * 128];  // 32 KB (one half of W)
  __shared__ __align__(16) float tl[96 * 128];  // 48 KB, XOR-swizzled
  int t = threadIdx.x;  // 256
  int node0 = blockIdx.x * 32; int g = node0 >> 9;
  int f32 = *flag;
  // ---- stage W half 0 (K-rows 0..63) ----
  if (f32) {
    const float4* Wg = (const float4*)W2_;
    float4* Wl = (float4*)Ws;
    #pragma unroll
    for (int i = 0; i < 8; i++) Wl[t + i * 256] = Wg[t + i * 256];
  } else {
    const ushort4* Wg = (const ushort4*)W2_;
    float4* Wl = (float4*)Ws;
    #pragma unroll
    for (int i = 0; i < 8; i++) {
      ushort4 h = Wg[t + i * 256];
      Wl[t + i * 256] = make_float4(h2f(h.x), h2f(h.y), h2f(h.z), h2f(h.w));
    }
  }
  // ---- phase 1: 8 groups of 32 lanes; each group builds 4 nodes (12 tl rows) ----
  {
    int lane = t & 31, grp = t >> 5;
    float4 b1v;
    if (f32) b1v = ((const float4*)b1_)[lane];
    else {
      ushort4 h = ((const ushort4*)b1_)[lane];
      b1v = make_float4(h2f(h.x), h2f(h.y), h2f(h.z), h2f(h.w));
    }
    #pragma unroll
    for (int nn = 0; nn < 4; nn++) {
      int n = grp * 4 + nn;
      int row = node0 + n;
      float4 ui = ((const float4*)(u + (size_t)row * 128))[lane];
      float4 vi = ((const float4*)(v + (size_t)row * 128))[lane];
      float4 base = make_float4(ui.x - vi.x + b1v.x, ui.y - vi.y + b1v.y,
                                ui.z - vi.z + b1v.z, ui.w - vi.w + b1v.w);
      #pragma unroll
      for (int k = 0; k < 3; k++) {
        int j = nbrp[row * 3 + k];
        float4 vj = ((const float4*)(v + (size_t)(g * Nn + j) * 128))[lane];
        float4 tv;
        tv.x = lrelu(base.x + vj.x); tv.y = lrelu(base.y + vj.y);
        tv.z = lrelu(base.z + vj.z); tv.w = lrelu(base.w + vj.w);
        int rr = n * 3 + k;
        *(float4*)&tl[TLS(rr, lane * 4)] = tv;
      }
    }
  }
  __syncthreads();
  int tx = t & 15, ty = t >> 4;   // 16 col-groups x 16 row-groups
  int colA = tx * 4;              // owns cols [colA, colA+3] and [64+colA, ...]
  int r0 = ty * 6;                // 6 rows/thread = nodes 2*ty, 2*ty+1
  float acc[6][8];
  #pragma unroll
  for (int r = 0; r < 6; r++)
    #pragma unroll
    for (int j = 0; j < 8; j++) acc[r][j] = 0.0f;
  // ---- compute half 0 (K = 0..63) ----
  for (int cc0 = 0; cc0 < 64; cc0 += 4) {
    float wv[4][8];
    #pragma unroll
    for (int cc = 0; cc < 4; cc++) {
      float4 wa = *(const float4*)&Ws[(cc0 + cc) * 128 + colA];
      float4 wb = *(const float4*)&Ws[(cc0 + cc) * 128 + 64 + colA];
      wv[cc][0] = wa.x; wv[cc][1] = wa.y; wv[cc][2] = wa.z; wv[cc][3] = wa.w;
      wv[cc][4] = wb.x; wv[cc][5] = wb.y; wv[cc][6] = wb.z; wv[cc][7] = wb.w;
    }
    #pragma unroll
    for (int r = 0; r < 6; r++) {
      int rr = r0 + r;
      float4 av = *(const float4*)&tl[TLS(rr, cc0)];
      #pragma unroll
      for (int j = 0; j < 8; j++)
        acc[r][j] += av.x * wv[0][j] + av.y * wv[1][j] + av.z * wv[2][j] + av.w * wv[3][j];
    }
  }
  __syncthreads();
  // ---- stage W half 1 (K-rows 64..127) ----
  if (f32) {
    const float4* Wg = (const float4*)W2_ + 2048;
    float4* Wl = (float4*)Ws;
    #pragma unroll
    for (int i = 0; i < 8; i++) Wl[t + i * 256] = Wg[t + i * 256];
  } else {
    const ushort4* Wg = (const ushort4*)W2_ + 2048;
    float4* Wl = (float4*)Ws;
    #pragma unroll
    for (int i = 0; i < 8; i++) {
      ushort4 h = Wg[t + i * 256];
      Wl[t + i * 256] = make_float4(h2f(h.x), h2f(h.y), h2f(h.z), h2f(h.w));
    }
  }
  __syncthreads();
  // ---- compute half 1 (K = 64..127) ----
  for (int cc0 = 0; cc0 < 64; cc0 += 4) {
    float wv[4][8];
    #pragma unroll
    for (int cc = 0; cc < 4; cc++) {
      float4 wa = *(const float4*)&Ws[(cc0 + cc) * 128 + colA];
      float4 wb = *(const float4*)&Ws[(cc0 + cc) * 128 + 64 + colA];
      wv[cc][0] = wa.x; wv[cc][1] = wa.y; wv[cc][2] = wa.z; wv[cc][3] = wa.w;
      wv[cc][4] = wb.x; wv[cc][5] = wb.y; wv[cc][6] = wb.z; wv[cc][7] = wb.w;
    }
    #pragma unroll
    for (int r = 0; r < 6; r++) {
      int rr = r0 + r;
      float4 av = *(const float4*)&tl[TLS(rr, 64 + cc0)];
      #pragma unroll
      for (int j = 0; j < 8; j++)
        acc[r][j] += av.x * wv[0][j] + av.y * wv[1][j] + av.z * wv[2][j] + av.w * wv[3][j];
    }
  }
  // ---- epilogue: bias + lrelu + max over 3 nbrs, per node ----
  float b2d[8];
  if (f32) {
    const float* b2p = (const float*)b2_;
    #pragma unroll
    for (int j = 0; j < 4; j++) { b2d[j] = b2p[colA + j]; b2d[4 + j] = b2p[64 + colA + j]; }
  } else {
    const bf16* b2p = (const bf16*)b2_;
    #pragma unroll
    for (int j = 0; j < 4; j++) { b2d[j] = b2f(b2p[colA + j]); b2d[4 + j] = b2f(b2p[64 + colA + j]); }
  }
  #pragma unroll
  for (int a = 0; a < 2; a++) {
    int rb = a * 3;
    float o[8];
    #pragma unroll
    for (int j = 0; j < 8; j++) {
      float m = lrelu(acc[rb][j] + b2d[j]);
      m = fmaxf(m, lrelu(acc[rb + 1][j] + b2d[j]));
      o[j] = fmaxf(m, lrelu(acc[rb + 2][j] + b2d[j]));
    }
    float* yp = &y[(size_t)(node0 + 2 * ty + a) * 128];
    *(float4*)(yp + colA) = make_float4(o[0], o[1], o[2], o[3]);
    *(float4*)(yp + 64 + colA) = make_float4(o[4], o[5], o[6], o[7]);
  }
}

// ---------- edgeconv2/3 ----------
__global__ void edge_max_kernel(const float* __restrict__ u, const float* __restrict__ v,
                                const int* __restrict__ nbrp, const void* __restrict__ bias_,
                                float* __restrict__ y, long boff, const int* __restrict__ flag) {
  int row = blockIdx.x; int g = row >> 9; int t = threadIdx.x;  // 128
  float ui = u[(size_t)row * 128 + t], vi = v[(size_t)row * 128 + t];
  float bd;
  if (*flag) bd = ((const float*)bias_ + boff)[t]; else bd = b2f(((const bf16*)bias_ + boff)[t]);
  float m = -3.4e38f;
  #pragma unroll
  for (int k = 0; k < 3; k++) {
    int j = nbrp[row * 3 + k];
    m = fmaxf(m, lrelu(ui - vi + v[(size_t)(g * Nn + j) * 128 + t] + bd));
  }
  y[(size_t)row * 128 + t] = m;
}

// ---------- chunked Gram matrix ----------
__global__ void gram_kernel(const float* __restrict__ y, float* __restrict__ G, int g0) {
  __shared__ float As[64][17], Bs[64][17];
  int bid = blockIdx.x;
  int gl = bid >> 6; int tt = bid & 63; int ti = tt >> 3; int tj = tt & 7;
  int g = g0 + gl;
  int t = threadIdx.x; int tx = t & 15, ty = t >> 4;
  const float* Yg = y + (size_t)g * Nn * Wd;
  float* Gg = G + (size_t)gl * Nn * Nn;
  float c[4][4];
  #pragma unroll
  for (int p = 0; p < 4; p++)
    #pragma unroll
    for (int q = 0; q < 4; q++) c[p][q] = 0.0f;
  for (int k0 = 0; k0 < 128; k0 += 16) {
    for (int idx = t; idx < 1024; idx += 256) {
      int r = idx >> 4, cc = idx & 15;
      As[r][cc] = Yg[(ti * 64 + r) * 128 + k0 + cc];
      Bs[r][cc] = Yg[(tj * 64 + r) * 128 + k0 + cc];
    }
    __syncthreads();
    for (int kk = 0; kk < 16; kk++) {
      float a[4], bb[4];
      #pragma unroll
      for (int p = 0; p < 4; p++) a[p] = As[ty * 4 + p][kk];
      #pragma unroll
      for (int q = 0; q < 4; q++) bb[q] = Bs[tx * 4 + q][kk];
      #pragma unroll
      for (int p = 0; p < 4; p++)
        #pragma unroll
        for (int q = 0; q < 4; q++) c[p][q] += a[p] * bb[q];
    }
    __syncthreads();
  }
  #pragma unroll
  for (int p = 0; p < 4; p++)
    #pragma unroll
    for (int q = 0; q < 4; q++)
      Gg[(size_t)(ti * 64 + ty * 4 + p) * Nn + tj * 64 + tx * 4 + q] = c[p][q];
}

// ---------- two-pass mean+max pool ----------
__global__ void pool1_kernel(const float* __restrict__ h, float* __restrict__ pp) {
  int b = blockIdx.x;                 // 256: g*8 + chunk
  int g = b >> 3, ch = b & 7;
  int t = threadIdx.x;                // 128
  const float* hg = h + (size_t)g * Nn * Wd + (size_t)ch * 64 * Wd;
  float s = 0.0f, m = -3.4e38f;
  #pragma unroll 4
  for (int n = 0; n < 64; n++) {
    float vv = hg[n * 128 + t];
    s += vv; m = fmaxf(m, vv);
  }
  pp[b * 256 + t] = s;
  pp[b * 256 + 128 + t] = m;
}

__global__ void pool2_kernel(const float* __restrict__ pp, float* __restrict__ z,
                             int meanoff, int maxoff) {
  int g = blockIdx.x; int t = threadIdx.x;  // 128
  float s = 0.0f, m = -3.4e38f;
  #pragma unroll
  for (int q = 0; q < 8; q++) {
    s += pp[(g * 8 + q) * 256 + t];
    m = fmaxf(m, pp[(g * 8 + q) * 256 + 128 + t]);
  }
  z[g * DIM2 + meanoff + t] = s / 512.0f;
  z[g * DIM2 + maxoff + t] = m;
}

// ---------- BatchNorm1d (batch stats), in place ----------
__global__ void bn_kernel(float* __restrict__ z, const void* __restrict__ gamma,
                          const void* __restrict__ beta, const int* __restrict__ flag) {
  int c = blockIdx.x * 256 + threadIdx.x;
  if (c >= DIM2) return;
  float s = 0.0f;
  for (int r = 0; r < Bg; r++) s += z[r * DIM2 + c];
  float mu = s / 32.0f;
  float v = 0.0f;
  for (int r = 0; r < Bg; r++) { float d = z[r * DIM2 + c] - mu; v += d * d; }
  float var = v / 32.0f;
  float gm, bt;
  if (*flag) { gm = ((const float*)gamma)[c]; bt = ((const float*)beta)[c]; }
  else       { gm = b2f(((const bf16*)gamma)[c]); bt = b2f(((const bf16*)beta)[c]); }
  float scale = gm / sqrtf(var + 1e-5f);
  for (int r = 0; r < Bg; r++) z[r * DIM2 + c] = (z[r * DIM2 + c] - mu) * scale + bt;
}

// ---------- head linear, K-split partial GEMM (no transpose) ----------
__global__ void hl_part_kernel(const float* __restrict__ zin, const float* __restrict__ Pin,
                               const void* __restrict__ bin_, const void* __restrict__ W_,
                               float* __restrict__ Pout, long Woff, long binoff, int mode,
                               const int* __restrict__ flag) {
  __shared__ __align__(16) float zs[32][KSL];  // 16 KB
  int t = threadIdx.x;  // 256
  int bd = blockIdx.x % 24, s = blockIdx.x / 24;
  int d0 = bd * 64, k0 = s * KSL;
  int f32 = *flag;
  if (mode == 0) {
    for (int idx = t; idx < 32 * KSL; idx += 256) {
      int r = idx >> 7, k = idx & 127;
      zs[r][k] = zin[r * DIM2 + k0 + k];
    }
  } else {
    // z[r][k] = lrelu(sum_s Pin[r][s][k0+k] + b[k0+k])
    for (int idx = t; idx < 32 * KSL / 4; idx += 256) {
      int r = idx >> 5, k4 = (idx & 31) * 4;
      float ax = 0.0f, ay = 0.0f, az = 0.0f, aw = 0.0f;
      const float* Pr = Pin + (size_t)r * NSL * DIM2 + k0 + k4;
      #pragma unroll
      for (int ss = 0; ss < NSL; ss++) {
        float4 p = *(const float4*)(Pr + (size_t)ss * DIM2);
        ax += p.x; ay += p.y; az += p.z; aw += p.w;
      }
      float b0, b1, b2, b3;
      if (f32) {
        const float* bp = (const float*)bin_ + binoff + k0 + k4;
        b0 = bp[0]; b1 = bp[1]; b2 = bp[2]; b3 = bp[3];
      } else {
        const bf16* bp = (const bf16*)bin_ + binoff + k0 + k4;
        b0 = b2f(bp[0]); b1 = b2f(bp[1]); b2 = b2f(bp[2]); b3 = b2f(bp[3]);
      }
      zs[r][k4 + 0] = lrelu(ax + b0);
      zs[r][k4 + 1] = lrelu(ay + b1);
      zs[r][k4 + 2] = lrelu(az + b2);
      zs[r][k4 + 3] = lrelu(aw + b3);
    }
  }
  __syncthreads();
  int lane = t & 63, rg = t >> 6;  // 64 cols per wave; 4 rowgroups of 8 rows
  int d = d0 + lane, r0 = rg * 8;
  float acc[8];
  #pragma unroll
  for (int i = 0; i < 8; i++) acc[i] = 0.0f;
  if (f32) {
    const float* W = (const float*)W_ + Woff;
    for (int k = 0; k < KSL; k += 4) {
      float w0 = W[(size_t)(k0 + k) * DIM2 + d];
      float w1 = W[(size_t)(k0 + k + 1) * DIM2 + d];
      float w2 = W[(size_t)(k0 + k + 2) * DIM2 + d];
      float w3 = W[(size_t)(k0 + k + 3) * DIM2 + d];
      #pragma unroll
      for (int i = 0; i < 8; i++) {
        float4 z4 = *(const float4*)&zs[r0 + i][k];
        acc[i] += z4.x * w0 + z4.y * w1 + z4.z * w2 + z4.w * w3;
      }
    }
  } else {
    const unsigned short* W = (const unsigned short*)W_ + Woff;
    for (int k = 0; k < KSL; k += 4) {
      float w0 = h2f(W[(size_t)(k0 + k) * DIM2 + d]);
      float w1 = h2f(W[(size_t)(k0 + k + 1) * DIM2 + d]);
      float w2 = h2f(W[(size_t)(k0 + k + 2) * DIM2 + d]);
      float w3 = h2f(W[(size_t)(k0 + k + 3) * DIM2 + d]);
      #pragma unroll
      for (int i = 0; i < 8; i++) {
        float4 z4 = *(const float4*)&zs[r0 + i][k];
        acc[i] += z4.x * w0 + z4.y * w1 + z4.z * w2 + z4.w * w3;
      }
    }
  }
  float* Po = Pout + (size_t)s * DIM2 + d;
  #pragma unroll
  for (int i = 0; i < 8; i++) Po[(size_t)(r0 + i) * NSL * DIM2] = acc[i];
}

// ---------- head: final 12-way reduce + bias + lrelu ----------
__global__ void hl_reduce_kernel(const float* __restrict__ Pin, const void* __restrict__ bin_,
                                 float* __restrict__ out, long binoff,
                                 const int* __restrict__ flag) {
  int idx = blockIdx.x * 256 + threadIdx.x;  // 192 blocks x 256 = 49152
  int r = idx / DIM2, d = idx - r * DIM2;
  float acc = 0.0f;
  const float* Pr = Pin + (size_t)r * NSL * DIM2 + d;
  #pragma unroll
  for (int s = 0; s < NSL; s++) acc += Pr[(size_t)s * DIM2];
  float b;
  if (*flag) b = ((const float*)bin_ + binoff)[d];
  else       b = b2f(((const bf16*)bin_ + binoff)[d]);
  out[r * DIM2 + d] = lrelu(acc + b);
}

// ---------- final ----------
__global__ void final_kernel(const float* __restrict__ zin, const void* __restrict__ outW,
                             const void* __restrict__ outb, void* __restrict__ out,
                             const int* __restrict__ flag) {
  __shared__ float red[256];
  int r = blockIdx.x, t = threadIdx.x;
  int f32 = *flag;
  float acc = 0.0f;
  if (f32) {
    const float* W = (const float*)outW;
    for (int c = t; c < DIM2; c += 256) acc += zin[r * DIM2 + c] * W[c];
  } else {
    const bf16* W = (const bf16*)outW;
    for (int c = t; c < DIM2; c += 256) acc += zin[r * DIM2 + c] * b2f(W[c]);
  }
  red[t] = acc; __syncthreads();
  for (int s = 128; s > 0; s >>= 1) { if (t < s) red[t] += red[t + s]; __syncthreads(); }
  if (t == 0) {
    float ob;
    if (f32) ob = ((const float*)outb)[0]; else ob = b2f(((const bf16*)outb)[0]);
    float val = red[0] + ob;
    if (f32) ((float*)out)[r] = val;
    else     ((bf16*)out)[r] = __float2bfloat16(val);
  }
}

extern "C" void kernel_launch(void* const* d_in, const int* in_sizes, int n_in,
                              void* d_out, int out_size, void* d_ws, size_t ws_size,
                              hipStream_t stream) {
  const void* x      = d_in[0];
  const void* tag1_W = d_in[2];
  const void* tag1_b = d_in[3];
  const void* tag_W  = d_in[4];
  const void* tag_b  = d_in[5];
  const void* p1_W1  = d_in[6];
  const void* p1_b1  = d_in[7];
  const void* p1_W2  = d_in[8];
  const void* p1_b2  = d_in[9];
  const void* pf_W   = d_in[10];
  const void* pf_b   = d_in[11];
  const void* bn_g   = d_in[12];
  const void* bn_b   = d_in[13];
  const void* lin_W  = d_in[14];
  const void* lin_b  = d_in[15];
  const void* out_W  = d_in[16];
  const void* out_b  = d_in[17];

  // ---- workspace layout: total 10,485,776 floats ≈ 40 MB ----
  float* ws = (float*)d_ws;
  float* XF   = ws + 0;                 // 98304
  float* M16  = ws + 98304;             // 98304 (dead after proj3 C=6 -> reused as PP)
  float* M26  = ws + 196608;            // 98304
  float* Z    = ws + 294912;            // 49152
  float* ZB   = ws + 344064;            // 49152
  int*   FLAG = (int*)(ws + 409600);    // 16
  int*   NBRP = (int*)(ws + 409616);    // 49152 ints
  int*   NBRG = (int*)(ws + 458768);    // 1,638,400 ints -> ends 2,097,168
  float* S0   = ws + 2097168;           // 4 slots x 2,097,152 floats (8 MB each)
  float* S1   = ws + 4194320;           // S0+S1 contiguous -> 16 MB G region
  float* S2   = ws + 6291472;
  float* S3   = ws + 8388624;           // ends 10,485,776 floats
  float* PA   = S0;                     // head partials ping (589,824 floats)
  float* PB   = S1;                     // head partials pong
  float* PP   = M16;                    // pool partials (65536 floats)

  detect_kernel<<<1, 64, 0, stream>>>((const unsigned short*)x, FLAG);
  convert_kernel<<<384, 256, 0, stream>>>(x, XF, Bg * Nn * Fdim, FLAG);
  knn100_kernel<<<Bg * Nn / 4, 256, 0, stream>>>(XF, NBRG);
  knn3_x_kernel<<<Bg * Nn / 16, 256, 0, stream>>>(XF, NBRP);

  // ---- TAG branch ----
  gm6_kernel<<<Bg, 512, 0, stream>>>(XF, NBRG, M16);
  gm6_kernel<<<Bg, 512, 0, stream>>>(M16, NBRG, M26);
  proj3_kernel<<<2048, 128, 0, stream>>>(XF, M16, M26, tag1_W, tag1_b, S0, FLAG);
  pool1_kernel<<<256, 128, 0, stream>>>(S0, PP);
  pool2_kernel<<<Bg, 128, 0, stream>>>(PP, Z, 0, 128);

  gm128_kernel<<<Bg * Nn / 8, 256, 0, stream>>>(S0, NBRG, S1);
  gm128_kernel<<<Bg * Nn / 8, 256, 0, stream>>>(S1, NBRG, S2);
  proj3_big_kernel<<<512, 256, 0, stream>>>(S0, S1, S2, tag_W, tag_b, S3, 0, 0, FLAG);
  pool1_kernel<<<256, 128, 0, stream>>>(S3, PP);
  pool2_kernel<<<Bg, 128, 0, stream>>>(PP, Z, 256, 384);

  gm128_kernel<<<Bg * Nn / 8, 256, 0, stream>>>(S3, NBRG, S1);
  gm128_kernel<<<Bg * Nn / 8, 256, 0, stream>>>(S1, NBRG, S2);
  proj3_big_kernel<<<512, 256, 0, stream>>>(S3, S1, S2, tag_W, tag_b, S0,
                                            3L * 128 * 128, 128, FLAG);
  pool1_kernel<<<256, 128, 0, stream>>>(S0, PP);
  pool2_kernel<<<Bg, 128, 0, stream>>>(PP, Z, 512, 640);

  // ---- point branch ----
  proj_dual_kernel<<<2048, 128, 0, stream>>>(XF, p1_W1, S0, S1, FLAG);
  edge_mlp1_kernel<<<512, 256, 0, stream>>>(S0, S1, NBRP, p1_W2, p1_b1, p1_b2, S2, FLAG);  // Y0=S2
  pool1_kernel<<<256, 128, 0, stream>>>(S2, PP);
  pool2_kernel<<<Bg, 128, 0, stream>>>(PP, Z, 768, 1152);

  for (int c = 0; c < Bg; c += GC16) {             // G=S0+S1 (U,V dead)
    gram_kernel<<<GC16 * 64, 256, 0, stream>>>(S2, S0, c);
    knn3_gram_kernel<<<GC16 * Nn / 16, 256, 0, stream>>>(S0, NBRP, c);
  }
  proj_dual_big_kernel<<<512, 256, 0, stream>>>(S2, pf_W, S0, S1, 0, FLAG);  // G dead
  edge_max_kernel<<<Bg * Nn, 128, 0, stream>>>(S0, S1, NBRP, pf_b, S3, 0, FLAG);  // Y1=S3
  pool1_kernel<<<256, 128, 0, stream>>>(S3, PP);
  pool2_kernel<<<Bg, 128, 0, stream>>>(PP, Z, 896, 1280);

  for (int c = 0; c < Bg; c += GC16) {             // G=S0+S1 (U,V dead)
    gram_kernel<<<GC16 * 64, 256, 0, stream>>>(S3, S0, c);
    knn3_gram_kernel<<<GC16 * Nn / 16, 256, 0, stream>>>(S0, NBRP, c);
  }
  proj_dual_big_kernel<<<512, 256, 0, stream>>>(S3, pf_W, S0, S1, 256L * 128, FLAG);  // G dead
  edge_max_kernel<<<Bg * Nn, 128, 0, stream>>>(S0, S1, NBRP, pf_b, S2, 128, FLAG);  // Y2=S2
  pool1_kernel<<<256, 128, 0, stream>>>(S2, PP);
  pool2_kernel<<<Bg, 128, 0, stream>>>(PP, Z, 1024, 1408);

  // ---- head: bn -> 5 x K-split linear (reduce fused into next stage) ----
  bn_kernel<<<6, 256, 0, stream>>>(Z, bn_g, bn_b, FLAG);
  hl_part_kernel<<<288, 256, 0, stream>>>(Z, nullptr, nullptr, lin_W, PA,
                                          0L * DIM2 * DIM2, 0L, 0, FLAG);
  hl_part_kernel<<<288, 256, 0, stream>>>(nullptr, PA, lin_b, lin_W, PB,
                                          1L * DIM2 * DIM2, 0L * DIM2, 1, FLAG);
  hl_part_kernel<<<288, 256, 0, stream>>>(nullptr, PB, lin_b, lin_W, PA,
                                          2L * DIM2 * DIM2, 1L * DIM2, 1, FLAG);
  hl_part_kernel<<<288, 256, 0, stream>>>(nullptr, PA, lin_b, lin_W, PB,
                                          3L * DIM2 * DIM2, 2L * DIM2, 1, FLAG);
  hl_part_kernel<<<288, 256, 0, stream>>>(nullptr, PB, lin_b, lin_W, PA,
                                          4L * DIM2 * DIM2, 3L * DIM2, 1, FLAG);
  hl_reduce_kernel<<<192, 256, 0, stream>>>(PA, lin_b, ZB, 4L * DIM2, FLAG);
  final_kernel<<<Bg, 256, 0, stream>>>(ZB, out_W, out_b, d_out, FLAG);
}

// Round 12
// 845.489 us; speedup vs baseline: 1.0163x; 1.0163x over previous
//
#include <hip/hip_runtime.h>
#include <hip/hip_bf16.h>

#define Bg 32
#define Nn 512
#define Fdim 6
#define Wd 128
#define KG 100
#define KP 3
#define DIM2 1536
#define GC16 16
#define NSL 12
#define KSL 128

typedef __hip_bfloat16 bf16;
typedef unsigned long long ull;

__device__ __forceinline__ float b2f(bf16 v) { return __bfloat162float(v); }
__device__ __forceinline__ float h2f(unsigned short h) { return __uint_as_float((unsigned)h << 16); }
__device__ __forceinline__ float lrelu(float v) { return v > 0.0f ? v : 0.01f * v; }

// ---------- dtype detection (f32=1 / bf16=0) ----------
__global__ void detect_kernel(const unsigned short* __restrict__ x, int* __restrict__ flag) {
  if (threadIdx.x == 0 && blockIdx.x == 0) {
    int big = 0;
    for (int i = 0; i < 512; i += 2) {
      unsigned short u = x[i];
      int e = (u >> 7) & 0xFF;
      if (e >= 140) big++;
    }
    *flag = (big > 20) ? 1 : 0;
  }
}

// ---------- convert x -> f32 ----------
__global__ void convert_kernel(const void* __restrict__ x, float* __restrict__ xf, int n,
                               const int* __restrict__ flag) {
  int i = blockIdx.x * 256 + threadIdx.x;
  if (i >= n) return;
  if (*flag) xf[i] = ((const float*)x)[i];
  else       xf[i] = b2f(((const bf16*)x)[i]);
}

// ---------- branchless sorted-3 insert ----------
__device__ __forceinline__ void ins3b(ull key, ull& k0, ull& k1, ull& k2) {
  ull M0 = k0 < key ? key : k0;  k0 = k0 < key ? k0 : key;
  ull M1 = k1 < M0 ? M0 : k1;    k1 = k1 < M0 ? k1 : M0;
  k2 = k2 < M1 ? k2 : M1;
}

// ---------- kNN k=100: one wave/row; ballot-popcount radix search ----------
__global__ void knn100_kernel(const float* __restrict__ xf, int* __restrict__ nbr) {
  __shared__ float xg[Nn * 7];
  __shared__ float sqv[Nn];
  int t = threadIdx.x; int w = t >> 6; int l = t & 63;
  int row0 = blockIdx.x * 4; int g = row0 >> 9;
  const float* xp = xf + g * (Nn * Fdim);
  for (int j = t; j < Nn; j += 256) {
    float s = 0.0f;
    #pragma unroll
    for (int c = 0; c < Fdim; c++) { float v = xp[j * Fdim + c]; xg[j * 7 + c] = v; s += v * v; }
    sqv[j] = s;
  }
  __syncthreads();
  int i = (row0 & 511) + w;
  float xi[Fdim];
  #pragma unroll
  for (int c = 0; c < Fdim; c++) xi[c] = xg[i * 7 + c];
  float sqi = sqv[i];
  unsigned m[8];
  #pragma unroll
  for (int ch = 0; ch < 8; ch++) {
    int j = ch * 64 + l;
    float dot = 0.0f;
    #pragma unroll
    for (int c = 0; c < Fdim; c++) dot += xi[c] * xg[j * 7 + c];
    float d = sqi + sqv[j] - 2.0f * dot;
    if (j == i) d += 1e10f;
    unsigned u = __float_as_uint(d);
    m[ch] = (u & 0x80000000u) ? ~u : (u | 0x80000000u);
  }
  unsigned T = 0u;
  for (int b = 31; b >= 0; b--) {
    unsigned mid = T | (1u << b);
    int c = 0;
    #pragma unroll
    for (int ch = 0; ch < 8; ch++) c += __popcll(__ballot(m[ch] < mid));
    if (c < KG) T = mid;
  }
  int* outp = nbr + ((size_t)(g * Nn + i)) * KG;
  ull lmask = (1ull << l) - 1ull;
  int base = 0;
  #pragma unroll
  for (int ch = 0; ch < 8; ch++) {
    bool less = m[ch] < T;
    ull bal = __ballot(less);
    if (less) outp[base + __popcll(bal & lmask)] = ch * 64 + l;
    base += __popcll(bal);
  }
  int need = KG - base;
  int eqb = 0;
  #pragma unroll
  for (int ch = 0; ch < 8; ch++) {
    bool eq = (m[ch] == T);
    ull bal = __ballot(eq);
    int gr = eqb + __popcll(bal & lmask);
    if (eq && gr < need) outp[base + gr] = ch * 64 + l;
    eqb += __popcll(bal);
  }
}

// ---------- kNN k=3 on coords: 16 lanes/row ----------
__global__ void knn3_x_kernel(const float* __restrict__ xf, int* __restrict__ nbr) {
  __shared__ float xg[Nn * 7];
  __shared__ float sqv[Nn];
  int t = threadIdx.x; int bid = blockIdx.x;
  int g = bid >> 5;
  const float* xp = xf + g * (Nn * Fdim);
  for (int j = t; j < Nn; j += 256) {
    float s = 0.0f;
    #pragma unroll
    for (int c = 0; c < Fdim; c++) { float v = xp[j * Fdim + c]; xg[j * 7 + c] = v; s += v * v; }
    sqv[j] = s;
  }
  __syncthreads();
  int lr = t >> 4; int sub = t & 15; int l = t & 63;
  int i = ((bid & 31) << 4) + lr;
  float xi[Fdim];
  #pragma unroll
  for (int c = 0; c < Fdim; c++) xi[c] = xg[i * 7 + c];
  float sqi = sqv[i];
  ull k0 = ~0ull, k1 = ~0ull, k2 = ~0ull;
  for (int jj = 0; jj < 32; jj++) {
    int s = (jj + l) & 31;
    int j = sub * 32 + s;
    float dot = 0.0f;
    #pragma unroll
    for (int c = 0; c < Fdim; c++) dot += xi[c] * xg[j * 7 + c];
    float d = sqi + sqv[j] - 2.0f * dot;
    if (j == i) d += 1e10f;
    unsigned u = __float_as_uint(d);
    unsigned m = (u & 0x80000000u) ? ~u : (u | 0x80000000u);
    ins3b(((ull)m << 32) | (unsigned)j, k0, k1, k2);
  }
  #pragma unroll
  for (int off = 1; off <= 8; off <<= 1) {
    ull b0 = __shfl_xor(k0, off, 64);
    ull b1 = __shfl_xor(k1, off, 64);
    ull b2 = __shfl_xor(k2, off, 64);
    ins3b(b0, k0, k1, k2); ins3b(b1, k0, k1, k2); ins3b(b2, k0, k1, k2);
  }
  if (sub == 0) {
    int row = g * Nn + i;
    nbr[row * 3 + 0] = (int)(k0 & 0xFFFFFFFFu);
    nbr[row * 3 + 1] = (int)(k1 & 0xFFFFFFFFu);
    nbr[row * 3 + 2] = (int)(k2 & 0xFFFFFFFFu);
  }
}

// ---------- kNN k=3 from chunked Gram ----------
__global__ void knn3_gram_kernel(const float* __restrict__ G, int* __restrict__ nbr, int g0) {
  __shared__ float sqv[Nn];
  int t = threadIdx.x; int bid = blockIdx.x;
  int gl = bid >> 5; int g = g0 + gl;
  const float* Gg = G + (size_t)gl * Nn * Nn;
  for (int j = t; j < Nn; j += 256) sqv[j] = Gg[(size_t)j * Nn + j];
  __syncthreads();
  int lr = t >> 4; int sub = t & 15; int l = t & 63;
  int i = ((bid & 31) << 4) + lr;
  float sqi = sqv[i];
  const float* Gr = Gg + (size_t)i * Nn;
  ull k0 = ~0ull, k1 = ~0ull, k2 = ~0ull;
  for (int jj = 0; jj < 32; jj++) {
    int s = (jj + l) & 31;
    int j = sub * 32 + s;
    float d = sqi + sqv[j] - 2.0f * Gr[j];
    if (j == i) d += 1e10f;
    unsigned u = __float_as_uint(d);
    unsigned m = (u & 0x80000000u) ? ~u : (u | 0x80000000u);
    ins3b(((ull)m << 32) | (unsigned)j, k0, k1, k2);
  }
  #pragma unroll
  for (int off = 1; off <= 8; off <<= 1) {
    ull b0 = __shfl_xor(k0, off, 64);
    ull b1 = __shfl_xor(k1, off, 64);
    ull b2 = __shfl_xor(k2, off, 64);
    ins3b(b0, k0, k1, k2); ins3b(b1, k0, k1, k2); ins3b(b2, k0, k1, k2);
  }
  if (sub == 0) {
    int row = g * Nn + i;
    nbr[row * 3 + 0] = (int)(k0 & 0xFFFFFFFFu);
    nbr[row * 3 + 1] = (int)(k1 & 0xFFFFFFFFu);
    nbr[row * 3 + 2] = (int)(k2 & 0xFFFFFFFFu);
  }
}

// ---------- neighbor-mean over 100, C=6 ----------
__global__ void gm6_kernel(const float* __restrict__ src, const int* __restrict__ nbr,
                           float* __restrict__ dst) {
  __shared__ float s[Nn * Fdim];
  int g = blockIdx.x; int t = threadIdx.x;  // 512
  const float* sp = src + g * (Nn * Fdim);
  for (int idx = t; idx < Nn * Fdim; idx += 512) s[idx] = sp[idx];
  __syncthreads();
  float acc[Fdim] = {0, 0, 0, 0, 0, 0};
  const int* nb = nbr + ((size_t)(g * Nn + t)) * KG;
  for (int k = 0; k < KG; k++) {
    int j = nb[k];
    #pragma unroll
    for (int c = 0; c < Fdim; c++) acc[c] += s[j * Fdim + c];
  }
  float* dp = dst + (size_t)(g * Nn + t) * Fdim;
  #pragma unroll
  for (int c = 0; c < Fdim; c++) dp[c] = acc[c] / 100.0f;
}

// ---------- neighbor-mean over 100, C=128: 8 rows/block, float4 gathers ----------
__global__ void gm128_kernel(const float* __restrict__ src, const int* __restrict__ nbr,
                             float* __restrict__ dst) {
  __shared__ int ids[8][KG];
  int t = threadIdx.x;  // 256
  int row0 = blockIdx.x * 8; int g = row0 >> 9;
  for (int idx = t; idx < 8 * KG; idx += 256) {
    int r = idx / KG, k = idx - r * KG;
    ids[r][k] = nbr[(size_t)(row0 + r) * KG + k];
  }
  __syncthreads();
  int lane = t & 31, r = t >> 5;  // r in 0..7
  const float4* sp = (const float4*)(src + (size_t)g * Nn * Wd);
  float ax = 0.0f, ay = 0.0f, az = 0.0f, aw = 0.0f;
  #pragma unroll 5
  for (int k = 0; k < KG; k++) {
    float4 v = sp[ids[r][k] * 32 + lane];
    ax += v.x; ay += v.y; az += v.z; aw += v.w;
  }
  float4 o = make_float4(ax / 100.0f, ay / 100.0f, az / 100.0f, aw / 100.0f);
  ((float4*)(dst + (size_t)(row0 + r) * Wd))[lane] = o;
}

// ---------- proj3 small (C=6 only; proven r10 path) ----------
__global__ void proj3_kernel(const float* __restrict__ in0, const float* __restrict__ in1,
                             const float* __restrict__ in2, const void* __restrict__ Wt_,
                             const void* __restrict__ bt_, float* __restrict__ out,
                             const int* __restrict__ flag) {
  __shared__ float s0[48], s1[48], s2[48];
  int t = threadIdx.x;  // 128
  int node0 = blockIdx.x * 8;
  int f32 = *flag;
  float acc[8] = {0, 0, 0, 0, 0, 0, 0, 0};
  float bd;
  if (t < 48) {
    s0[t] = in0[(size_t)node0 * 6 + t];
    s1[t] = in1[(size_t)node0 * 6 + t];
    s2[t] = in2[(size_t)node0 * 6 + t];
  }
  __syncthreads();
  if (f32) {
    const float* W = (const float*)Wt_;
    for (int c = 0; c < 6; c++) {
      float w0 = W[c * 128 + t], w1 = W[(6 + c) * 128 + t], w2 = W[(12 + c) * 128 + t];
      #pragma unroll
      for (int n = 0; n < 8; n++)
        acc[n] += s0[n * 6 + c] * w0 + s1[n * 6 + c] * w1 + s2[n * 6 + c] * w2;
    }
    bd = ((const float*)bt_)[t];
  } else {
    const bf16* W = (const bf16*)Wt_;
    for (int c = 0; c < 6; c++) {
      float w0 = b2f(W[c * 128 + t]), w1 = b2f(W[(6 + c) * 128 + t]), w2 = b2f(W[(12 + c) * 128 + t]);
      #pragma unroll
      for (int n = 0; n < 8; n++)
        acc[n] += s0[n * 6 + c] * w0 + s1[n * 6 + c] * w1 + s2[n * 6 + c] * w2;
    }
    bd = b2f(((const bf16*)bt_)[t]);
  }
  #pragma unroll
  for (int n = 0; n < 8; n++)
    out[(size_t)(node0 + n) * 128 + t] = lrelu(acc[n] + bd);
}

// ---------- proj3 big (C=128): chunk-staged W in LDS (64 rows, single-buffered) ----------
__global__ void proj3_big_kernel(const float* __restrict__ in0, const float* __restrict__ in1,
                                 const float* __restrict__ in2, const void* __restrict__ Wt_,
                                 const void* __restrict__ bt_, float* __restrict__ out,
                                 long Woff, long boff, const int* __restrict__ flag) {
  __shared__ __align__(16) float sa[3][32 * 128];  // 48 KB
  __shared__ __align__(16) float Wc[64 * 128];     // 32 KB chunk
  int t = threadIdx.x;  // 256
  int node0 = blockIdx.x * 32;
  int f32 = *flag;
  // ---- stage inputs ----
  {
    const float4* q0 = (const float4*)(in0 + (size_t)node0 * 128);
    const float4* q1 = (const float4*)(in1 + (size_t)node0 * 128);
    const float4* q2 = (const float4*)(in2 + (size_t)node0 * 128);
    float4* s0 = (float4*)sa[0]; float4* s1 = (float4*)sa[1]; float4* s2 = (float4*)sa[2];
    #pragma unroll
    for (int it = 0; it < 4; it++) {
      s0[t + it * 256] = q0[t + it * 256];
      s1[t + it * 256] = q1[t + it * 256];
      s2[t + it * 256] = q2[t + it * 256];
    }
  }
  int tx = t & 31, ty = t >> 5;
  int col0 = tx * 4, n0 = ty * 4;
  float acc[4][4];
  #pragma unroll
  for (int n = 0; n < 4; n++)
    #pragma unroll
    for (int j = 0; j < 4; j++) acc[n][j] = 0.0f;
  for (int half = 0; half < 6; half++) {   // a = half>>1, 64-row half h = half&1
    int a = half >> 1, h = half & 1;
    {
      float4* Wl = (float4*)Wc;
      if (f32) {
        const float4* Wg = (const float4*)((const float*)Wt_ + Woff
                                           + (size_t)a * 16384 + (size_t)h * 8192);
        #pragma unroll
        for (int i = 0; i < 8; i++) Wl[t + i * 256] = Wg[t + i * 256];
      } else {
        const ushort4* Wg = (const ushort4*)((const unsigned short*)Wt_ + Woff
                                             + (size_t)a * 16384 + (size_t)h * 8192);
        #pragma unroll
        for (int i = 0; i < 8; i++) {
          ushort4 hh = Wg[t + i * 256];
          Wl[t + i * 256] = make_float4(h2f(hh.x), h2f(hh.y), h2f(hh.z), h2f(hh.w));
        }
      }
    }
    __syncthreads();   // chunk (and, on half=0, inputs) visible
    const float* sp = sa[a];
    int cbase = h * 64;
    #pragma unroll 4
    for (int cc0 = 0; cc0 < 64; cc0 += 4) {
      float wv[4][4];
      #pragma unroll
      for (int cc = 0; cc < 4; cc++) {
        float4 w4 = *(const float4*)&Wc[(cc0 + cc) * 128 + col0];
        wv[cc][0] = w4.x; wv[cc][1] = w4.y; wv[cc][2] = w4.z; wv[cc][3] = w4.w;
      }
      int c0 = cbase + cc0;
      #pragma unroll
      for (int n = 0; n < 4; n++) {
        float4 av = *(const float4*)&sp[(n0 + n) * 128 + c0];
        #pragma unroll
        for (int j = 0; j < 4; j++)
          acc[n][j] += av.x * wv[0][j] + av.y * wv[1][j] + av.z * wv[2][j] + av.w * wv[3][j];
      }
    }
    __syncthreads();   // protect Wc before next stage
  }
  float bdv[4];
  if (f32) {
    const float* bt = (const float*)bt_ + boff;
    #pragma unroll
    for (int j = 0; j < 4; j++) bdv[j] = bt[col0 + j];
  } else {
    const bf16* bt = (const bf16*)bt_ + boff;
    #pragma unroll
    for (int j = 0; j < 4; j++) bdv[j] = b2f(bt[col0 + j]);
  }
  #pragma unroll
  for (int n = 0; n < 4; n++) {
    float4 ov;
    ov.x = lrelu(acc[n][0] + bdv[0]); ov.y = lrelu(acc[n][1] + bdv[1]);
    ov.z = lrelu(acc[n][2] + bdv[2]); ov.w = lrelu(acc[n][3] + bdv[3]);
    *(float4*)&out[(size_t)(node0 + n0 + n) * 128 + col0] = ov;
  }
}

// ---------- proj_dual small (C=6 only; proven r10 path) ----------
__global__ void proj_dual_kernel(const float* __restrict__ in, const void* __restrict__ Wt_,
                                 float* __restrict__ u, float* __restrict__ v,
                                 const int* __restrict__ flag) {
  __shared__ float s0[48];
  int t = threadIdx.x; int node0 = blockIdx.x * 8;
  int f32 = *flag;
  float au[8] = {0, 0, 0, 0, 0, 0, 0, 0};
  float av[8] = {0, 0, 0, 0, 0, 0, 0, 0};
  if (t < 48) s0[t] = in[(size_t)node0 * 6 + t];
  __syncthreads();
  if (f32) {
    const float* W = (const float*)Wt_;
    for (int c = 0; c < 6; c++) {
      float wa = W[c * 128 + t], wb = W[(6 + c) * 128 + t];
      #pragma unroll
      for (int n = 0; n < 8; n++) { float x = s0[n * 6 + c]; au[n] += x * wa; av[n] += x * wb; }
    }
  } else {
    const bf16* W = (const bf16*)Wt_;
    for (int c = 0; c < 6; c++) {
      float wa = b2f(W[c * 128 + t]), wb = b2f(W[(6 + c) * 128 + t]);
      #pragma unroll
      for (int n = 0; n < 8; n++) { float x = s0[n * 6 + c]; au[n] += x * wa; av[n] += x * wb; }
    }
  }
  #pragma unroll
  for (int n = 0; n < 8; n++) {
    u[(size_t)(node0 + n) * 128 + t] = au[n];
    v[(size_t)(node0 + n) * 128 + t] = av[n];
  }
}

// ---------- proj_dual big (C=128): chunk-staged W in LDS (4 x 64-row chunks) ----------
__global__ void proj_dual_big_kernel(const float* __restrict__ in, const void* __restrict__ Wt_,
                                     float* __restrict__ u, float* __restrict__ v,
                                     long Woff, const int* __restrict__ flag) {
  __shared__ __align__(16) float sa[32 * 128];     // 16 KB
  __shared__ __align__(16) float Wc[64 * 128];     // 32 KB chunk
  int t = threadIdx.x;  // 256
  int node0 = blockIdx.x * 32;
  int f32 = *flag;
  {
    const float4* qp = (const float4*)(in + (size_t)node0 * 128);
    float4* s0 = (float4*)sa;
    #pragma unroll
    for (int it = 0; it < 4; it++) s0[t + it * 256] = qp[t + it * 256];
  }
  int tx = t & 31, ty = t >> 5;
  int col0 = tx * 4, n0 = ty * 4;
  float accu[4][4], accv[4][4];
  #pragma unroll
  for (int n = 0; n < 4; n++)
    #pragma unroll
    for (int j = 0; j < 4; j++) { accu[n][j] = 0.0f; accv[n][j] = 0.0f; }
  for (int q = 0; q < 4; q++) {
    {
      float4* Wl = (float4*)Wc;
      if (f32) {
        const float4* Wg = (const float4*)((const float*)Wt_ + Woff + (size_t)q * 8192);
        #pragma unroll
        for (int i = 0; i < 8; i++) Wl[t + i * 256] = Wg[t + i * 256];
      } else {
        const ushort4* Wg = (const ushort4*)((const unsigned short*)Wt_ + Woff
                                             + (size_t)q * 8192);
        #pragma unroll
        for (int i = 0; i < 8; i++) {
          ushort4 hh = Wg[t + i * 256];
          Wl[t + i * 256] = make_float4(h2f(hh.x), h2f(hh.y), h2f(hh.z), h2f(hh.w));
        }
      }
    }
    __syncthreads();
    int cbase = (q & 1) * 64;
    if (q < 2) {
      #pragma unroll 4
      for (int cc0 = 0; cc0 < 64; cc0 += 4) {
        float wv[4][4];
        #pragma unroll
        for (int cc = 0; cc < 4; cc++) {
          float4 w4 = *(const float4*)&Wc[(cc0 + cc) * 128 + col0];
          wv[cc][0] = w4.x; wv[cc][1] = w4.y; wv[cc][2] = w4.z; wv[cc][3] = w4.w;
        }
        int c0 = cbase + cc0;
        #pragma unroll
        for (int n = 0; n < 4; n++) {
          float4 av = *(const float4*)&sa[(n0 + n) * 128 + c0];
          #pragma unroll
          for (int j = 0; j < 4; j++)
            accu[n][j] += av.x * wv[0][j] + av.y * wv[1][j] + av.z * wv[2][j] + av.w * wv[3][j];
        }
      }
    } else {
      #pragma unroll 4
      for (int cc0 = 0; cc0 < 64; cc0 += 4) {
        float wv[4][4];
        #pragma unroll
        for (int cc = 0; cc < 4; cc++) {
          float4 w4 = *(const float4*)&Wc[(cc0 + cc) * 128 + col0];
          wv[cc][0] = w4.x; wv[cc][1] = w4.y; wv[cc][2] = w4.z; wv[cc][3] = w4.w;
        }
        int c0 = cbase + cc0;
        #pragma unroll
        for (int n = 0; n < 4; n++) {
          float4 av = *(const float4*)&sa[(n0 + n) * 128 + c0];
          #pragma unroll
          for (int j = 0; j < 4; j++)
            accv[n][j] += av.x * wv[0][j] + av.y * wv[1][j] + av.z * wv[2][j] + av.w * wv[3][j];
        }
      }
    }
    __syncthreads();
  }
  #pragma unroll
  for (int n = 0; n < 4; n++) {
    *(float4*)&u[(size_t)(node0 + n0 + n) * 128 + col0] = *(float4*)accu[n];
    *(float4*)&v[(size_t)(node0 + n0 + n) * 128 + col0] = *(float4*)accv[n];
  }
}

// ---------- edgeconv1: half-W LDS staging (2 x 32 KB), single-buffered ----------
// r11 post-mortem: 6x8/32-node tile arc (r9-r11) all landed >=51 us vs this
// variant's 47 us (r8-measured) -- occupancy/latency dominates, not LDS reads.
// Pre-committed fallback honored: reverted to r8 variant. PARKED.
__global__ void edge_mlp1_kernel(const float* __restrict__ u, const float* __restrict__ v,
                                 const int* __restrict__ nbrp, const void* __restrict__ W2_,
                                 const void* __restrict__ b1_, const void* __restrict__ b2_,
                                 float* __restrict__ y, const int* __restrict__ flag) {
  __shared__ __align__(16) float Ws[64 * 128];  // 32 KB (one half of W)
  __shared__ __align__(16) float tl[24][128];   // 12 KB
  int t = threadIdx.x;  // 256
  int node0 = blockIdx.x * 8; int g = node0 >> 9;
  int f32 = *flag;
  // ---- stage W half 0 (K-rows 0..63) ----
  if (f32) {
    const float4* Wg = (const float4*)W2_;
    float4* Wl = (float4*)Ws;
    #pragma unroll
    for (int i = 0; i < 8; i++) Wl[t + i * 256] = Wg[t + i * 256];
  } else {
    const ushort4* Wg = (const ushort4*)W2_;
    float4* Wl = (float4*)Ws;
    #pragma unroll
    for (int i = 0; i < 8; i++) {
      ushort4 h = Wg[t + i * 256];
      Wl[t + i * 256] = make_float4(h2f(h.x), h2f(h.y), h2f(h.z), h2f(h.w));
    }
  }
  // ---- phase 1: group n = t>>5 builds tl rows 3n..3n+2 via float4 ----
  {
    int lane = t & 31, n = t >> 5;
    int row = node0 + n;
    float4 ui = ((const float4*)(u + (size_t)row * 128))[lane];
    float4 vi = ((const float4*)(v + (size_t)row * 128))[lane];
    float4 b1v;
    if (f32) b1v = ((const float4*)b1_)[lane];
    else {
      ushort4 h = ((const ushort4*)b1_)[lane];
      b1v = make_float4(h2f(h.x), h2f(h.y), h2f(h.z), h2f(h.w));
    }
    float4 base = make_float4(ui.x - vi.x + b1v.x, ui.y - vi.y + b1v.y,
                              ui.z - vi.z + b1v.z, ui.w - vi.w + b1v.w);
    #pragma unroll
    for (int k = 0; k < 3; k++) {
      int j = nbrp[row * 3 + k];
      float4 vj = ((const float4*)(v + (size_t)(g * Nn + j) * 128))[lane];
      float4 tv;
      tv.x = lrelu(base.x + vj.x); tv.y = lrelu(base.y + vj.y);
      tv.z = lrelu(base.z + vj.z); tv.w = lrelu(base.w + vj.w);
      *(float4*)&tl[n * 3 + k][lane * 4] = tv;
    }
  }
  __syncthreads();
  int tx = t & 31, ty = t >> 5;
  int col0 = tx * 4;
  float acc[3][4];
  #pragma unroll
  for (int k = 0; k < 3; k++)
    #pragma unroll
    for (int j = 0; j < 4; j++) acc[k][j] = 0.0f;
  // ---- compute half 0 (K = 0..63) ----
  #pragma unroll 4
  for (int cc0 = 0; cc0 < 64; cc0 += 4) {
    float wv[4][4];
    #pragma unroll
    for (int cc = 0; cc < 4; cc++) {
      float4 w4 = *(const float4*)&Ws[(cc0 + cc) * 128 + col0];
      wv[cc][0] = w4.x; wv[cc][1] = w4.y; wv[cc][2] = w4.z; wv[cc][3] = w4.w;
    }
    #pragma unroll
    for (int k = 0; k < 3; k++) {
      float4 av = *(const float4*)&tl[ty * 3 + k][cc0];
      #pragma unroll
      for (int j = 0; j < 4; j++)
        acc[k][j] += av.x * wv[0][j] + av.y * wv[1][j] + av.z * wv[2][j] + av.w * wv[3][j];
    }
  }
  __syncthreads();
  // ---- stage W half 1 (K-rows 64..127) ----
  if (f32) {
    const float4* Wg = (const float4*)W2_ + 2048;
    float4* Wl = (float4*)Ws;
    #pragma unroll
    for (int i = 0; i < 8; i++) Wl[t + i * 256] = Wg[t + i * 256];
  } else {
    const ushort4* Wg = (const ushort4*)W2_ + 2048;
    float4* Wl = (float4*)Ws;
    #pragma unroll
    for (int i = 0; i < 8; i++) {
      ushort4 h = Wg[t + i * 256];
      Wl[t + i * 256] = make_float4(h2f(h.x), h2f(h.y), h2f(h.z), h2f(h.w));
    }
  }
  __syncthreads();
  // ---- compute half 1 (K = 64..127) ----
  #pragma unroll 4
  for (int cc0 = 0; cc0 < 64; cc0 += 4) {
    float wv[4][4];
    #pragma unroll
    for (int cc = 0; cc < 4; cc++) {
      float4 w4 = *(const float4*)&Ws[(cc0 + cc) * 128 + col0];
      wv[cc][0] = w4.x; wv[cc][1] = w4.y; wv[cc][2] = w4.z; wv[cc][3] = w4.w;
    }
    #pragma unroll
    for (int k = 0; k < 3; k++) {
      float4 av = *(const float4*)&tl[ty * 3 + k][64 + cc0];
      #pragma unroll
      for (int j = 0; j < 4; j++)
        acc[k][j] += av.x * wv[0][j] + av.y * wv[1][j] + av.z * wv[2][j] + av.w * wv[3][j];
    }
  }
  float b2d[4];
  if (f32) {
    const float* b2p = (const float*)b2_;
    #pragma unroll
    for (int j = 0; j < 4; j++) b2d[j] = b2p[col0 + j];
  } else {
    const bf16* b2p = (const bf16*)b2_;
    #pragma unroll
    for (int j = 0; j < 4; j++) b2d[j] = b2f(b2p[col0 + j]);
  }
  float4 ov;
  {
    float m0 = lrelu(acc[0][0] + b2d[0]);
    m0 = fmaxf(m0, lrelu(acc[1][0] + b2d[0]));
    ov.x = fmaxf(m0, lrelu(acc[2][0] + b2d[0]));
    float m1 = lrelu(acc[0][1] + b2d[1]);
    m1 = fmaxf(m1, lrelu(acc[1][1] + b2d[1]));
    ov.y = fmaxf(m1, lrelu(acc[2][1] + b2d[1]));
    float m2 = lrelu(acc[0][2] + b2d[2]);
    m2 = fmaxf(m2, lrelu(acc[1][2] + b2d[2]));
    ov.z = fmaxf(m2, lrelu(acc[2][2] + b2d[2]));
    float m3 = lrelu(acc[0][3] + b2d[3]);
    m3 = fmaxf(m3, lrelu(acc[1][3] + b2d[3]));
    ov.w = fmaxf(m3, lrelu(acc[2][3] + b2d[3]));
  }
  *(float4*)&y[(size_t)(node0 + ty) * 128 + col0] = ov;
}

// ---------- edgeconv2/3 ----------
__global__ void edge_max_kernel(const float* __restrict__ u, const float* __restrict__ v,
                                const int* __restrict__ nbrp, const void* __restrict__ bias_,
                                float* __restrict__ y, long boff, const int* __restrict__ flag) {
  int row = blockIdx.x; int g = row >> 9; int t = threadIdx.x;  // 128
  float ui = u[(size_t)row * 128 + t], vi = v[(size_t)row * 128 + t];
  float bd;
  if (*flag) bd = ((const float*)bias_ + boff)[t]; else bd = b2f(((const bf16*)bias_ + boff)[t]);
  float m = -3.4e38f;
  #pragma unroll
  for (int k = 0; k < 3; k++) {
    int j = nbrp[row * 3 + k];
    m = fmaxf(m, lrelu(ui - vi + v[(size_t)(g * Nn + j) * 128 + t] + bd));
  }
  y[(size_t)row * 128 + t] = m;
}

// ---------- chunked Gram matrix ----------
__global__ void gram_kernel(const float* __restrict__ y, float* __restrict__ G, int g0) {
  __shared__ float As[64][17], Bs[64][17];
  int bid = blockIdx.x;
  int gl = bid >> 6; int tt = bid & 63; int ti = tt >> 3; int tj = tt & 7;
  int g = g0 + gl;
  int t = threadIdx.x; int tx = t & 15, ty = t >> 4;
  const float* Yg = y + (size_t)g * Nn * Wd;
  float* Gg = G + (size_t)gl * Nn * Nn;
  float c[4][4];
  #pragma unroll
  for (int p = 0; p < 4; p++)
    #pragma unroll
    for (int q = 0; q < 4; q++) c[p][q] = 0.0f;
  for (int k0 = 0; k0 < 128; k0 += 16) {
    for (int idx = t; idx < 1024; idx += 256) {
      int r = idx >> 4, cc = idx & 15;
      As[r][cc] = Yg[(ti * 64 + r) * 128 + k0 + cc];
      Bs[r][cc] = Yg[(tj * 64 + r) * 128 + k0 + cc];
    }
    __syncthreads();
    for (int kk = 0; kk < 16; kk++) {
      float a[4], bb[4];
      #pragma unroll
      for (int p = 0; p < 4; p++) a[p] = As[ty * 4 + p][kk];
      #pragma unroll
      for (int q = 0; q < 4; q++) bb[q] = Bs[tx * 4 + q][kk];
      #pragma unroll
      for (int p = 0; p < 4; p++)
        #pragma unroll
        for (int q = 0; q < 4; q++) c[p][q] += a[p] * bb[q];
    }
    __syncthreads();
  }
  #pragma unroll
  for (int p = 0; p < 4; p++)
    #pragma unroll
    for (int q = 0; q < 4; q++)
      Gg[(size_t)(ti * 64 + ty * 4 + p) * Nn + tj * 64 + tx * 4 + q] = c[p][q];
}

// ---------- two-pass mean+max pool ----------
__global__ void pool1_kernel(const float* __restrict__ h, float* __restrict__ pp) {
  int b = blockIdx.x;                 // 256: g*8 + chunk
  int g = b >> 3, ch = b & 7;
  int t = threadIdx.x;                // 128
  const float* hg = h + (size_t)g * Nn * Wd + (size_t)ch * 64 * Wd;
  float s = 0.0f, m = -3.4e38f;
  #pragma unroll 4
  for (int n = 0; n < 64; n++) {
    float vv = hg[n * 128 + t];
    s += vv; m = fmaxf(m, vv);
  }
  pp[b * 256 + t] = s;
  pp[b * 256 + 128 + t] = m;
}

__global__ void pool2_kernel(const float* __restrict__ pp, float* __restrict__ z,
                             int meanoff, int maxoff) {
  int g = blockIdx.x; int t = threadIdx.x;  // 128
  float s = 0.0f, m = -3.4e38f;
  #pragma unroll
  for (int q = 0; q < 8; q++) {
    s += pp[(g * 8 + q) * 256 + t];
    m = fmaxf(m, pp[(g * 8 + q) * 256 + 128 + t]);
  }
  z[g * DIM2 + meanoff + t] = s / 512.0f;
  z[g * DIM2 + maxoff + t] = m;
}

// ---------- BatchNorm1d (batch stats), in place ----------
__global__ void bn_kernel(float* __restrict__ z, const void* __restrict__ gamma,
                          const void* __restrict__ beta, const int* __restrict__ flag) {
  int c = blockIdx.x * 256 + threadIdx.x;
  if (c >= DIM2) return;
  float s = 0.0f;
  for (int r = 0; r < Bg; r++) s += z[r * DIM2 + c];
  float mu = s / 32.0f;
  float v = 0.0f;
  for (int r = 0; r < Bg; r++) { float d = z[r * DIM2 + c] - mu; v += d * d; }
  float var = v / 32.0f;
  float gm, bt;
  if (*flag) { gm = ((const float*)gamma)[c]; bt = ((const float*)beta)[c]; }
  else       { gm = b2f(((const bf16*)gamma)[c]); bt = b2f(((const bf16*)beta)[c]); }
  float scale = gm / sqrtf(var + 1e-5f);
  for (int r = 0; r < Bg; r++) z[r * DIM2 + c] = (z[r * DIM2 + c] - mu) * scale + bt;
}

// ---------- head linear, K-split partial GEMM (no transpose) ----------
__global__ void hl_part_kernel(const float* __restrict__ zin, const float* __restrict__ Pin,
                               const void* __restrict__ bin_, const void* __restrict__ W_,
                               float* __restrict__ Pout, long Woff, long binoff, int mode,
                               const int* __restrict__ flag) {
  __shared__ __align__(16) float zs[32][KSL];  // 16 KB
  int t = threadIdx.x;  // 256
  int bd = blockIdx.x % 24, s = blockIdx.x / 24;
  int d0 = bd * 64, k0 = s * KSL;
  int f32 = *flag;
  if (mode == 0) {
    for (int idx = t; idx < 32 * KSL; idx += 256) {
      int r = idx >> 7, k = idx & 127;
      zs[r][k] = zin[r * DIM2 + k0 + k];
    }
  } else {
    // z[r][k] = lrelu(sum_s Pin[r][s][k0+k] + b[k0+k])
    for (int idx = t; idx < 32 * KSL / 4; idx += 256) {
      int r = idx >> 5, k4 = (idx & 31) * 4;
      float ax = 0.0f, ay = 0.0f, az = 0.0f, aw = 0.0f;
      const float* Pr = Pin + (size_t)r * NSL * DIM2 + k0 + k4;
      #pragma unroll
      for (int ss = 0; ss < NSL; ss++) {
        float4 p = *(const float4*)(Pr + (size_t)ss * DIM2);
        ax += p.x; ay += p.y; az += p.z; aw += p.w;
      }
      float b0, b1, b2, b3;
      if (f32) {
        const float* bp = (const float*)bin_ + binoff + k0 + k4;
        b0 = bp[0]; b1 = bp[1]; b2 = bp[2]; b3 = bp[3];
      } else {
        const bf16* bp = (const bf16*)bin_ + binoff + k0 + k4;
        b0 = b2f(bp[0]); b1 = b2f(bp[1]); b2 = b2f(bp[2]); b3 = b2f(bp[3]);
      }
      zs[r][k4 + 0] = lrelu(ax + b0);
      zs[r][k4 + 1] = lrelu(ay + b1);
      zs[r][k4 + 2] = lrelu(az + b2);
      zs[r][k4 + 3] = lrelu(aw + b3);
    }
  }
  __syncthreads();
  int lane = t & 63, rg = t >> 6;  // 64 cols per wave; 4 rowgroups of 8 rows
  int d = d0 + lane, r0 = rg * 8;
  float acc[8];
  #pragma unroll
  for (int i = 0; i < 8; i++) acc[i] = 0.0f;
  if (f32) {
    const float* W = (const float*)W_ + Woff;
    for (int k = 0; k < KSL; k += 4) {
      float w0 = W[(size_t)(k0 + k) * DIM2 + d];
      float w1 = W[(size_t)(k0 + k + 1) * DIM2 + d];
      float w2 = W[(size_t)(k0 + k + 2) * DIM2 + d];
      float w3 = W[(size_t)(k0 + k + 3) * DIM2 + d];
      #pragma unroll
      for (int i = 0; i < 8; i++) {
        float4 z4 = *(const float4*)&zs[r0 + i][k];
        acc[i] += z4.x * w0 + z4.y * w1 + z4.z * w2 + z4.w * w3;
      }
    }
  } else {
    const unsigned short* W = (const unsigned short*)W_ + Woff;
    for (int k = 0; k < KSL; k += 4) {
      float w0 = h2f(W[(size_t)(k0 + k) * DIM2 + d]);
      float w1 = h2f(W[(size_t)(k0 + k + 1) * DIM2 + d]);
      float w2 = h2f(W[(size_t)(k0 + k + 2) * DIM2 + d]);
      float w3 = h2f(W[(size_t)(k0 + k + 3) * DIM2 + d]);
      #pragma unroll
      for (int i = 0; i < 8; i++) {
        float4 z4 = *(const float4*)&zs[r0 + i][k];
        acc[i] += z4.x * w0 + z4.y * w1 + z4.z * w2 + z4.w * w3;
      }
    }
  }
  float* Po = Pout + (size_t)s * DIM2 + d;
  #pragma unroll
  for (int i = 0; i < 8; i++) Po[(size_t)(r0 + i) * NSL * DIM2] = acc[i];
}

// ---------- head: final 12-way reduce + bias + lrelu ----------
__global__ void hl_reduce_kernel(const float* __restrict__ Pin, const void* __restrict__ bin_,
                                 float* __restrict__ out, long binoff,
                                 const int* __restrict__ flag) {
  int idx = blockIdx.x * 256 + threadIdx.x;  // 192 blocks x 256 = 49152
  int r = idx / DIM2, d = idx - r * DIM2;
  float acc = 0.0f;
  const float* Pr = Pin + (size_t)r * NSL * DIM2 + d;
  #pragma unroll
  for (int s = 0; s < NSL; s++) acc += Pr[(size_t)s * DIM2];
  float b;
  if (*flag) b = ((const float*)bin_ + binoff)[d];
  else       b = b2f(((const bf16*)bin_ + binoff)[d]);
  out[r * DIM2 + d] = lrelu(acc + b);
}

// ---------- final ----------
__global__ void final_kernel(const float* __restrict__ zin, const void* __restrict__ outW,
                             const void* __restrict__ outb, void* __restrict__ out,
                             const int* __restrict__ flag) {
  __shared__ float red[256];
  int r = blockIdx.x, t = threadIdx.x;
  int f32 = *flag;
  float acc = 0.0f;
  if (f32) {
    const float* W = (const float*)outW;
    for (int c = t; c < DIM2; c += 256) acc += zin[r * DIM2 + c] * W[c];
  } else {
    const bf16* W = (const bf16*)outW;
    for (int c = t; c < DIM2; c += 256) acc += zin[r * DIM2 + c] * b2f(W[c]);
  }
  red[t] = acc; __syncthreads();
  for (int s = 128; s > 0; s >>= 1) { if (t < s) red[t] += red[t + s]; __syncthreads(); }
  if (t == 0) {
    float ob;
    if (f32) ob = ((const float*)outb)[0]; else ob = b2f(((const bf16*)outb)[0]);
    float val = red[0] + ob;
    if (f32) ((float*)out)[r] = val;
    else     ((bf16*)out)[r] = __float2bfloat16(val);
  }
}

extern "C" void kernel_launch(void* const* d_in, const int* in_sizes, int n_in,
                              void* d_out, int out_size, void* d_ws, size_t ws_size,
                              hipStream_t stream) {
  const void* x      = d_in[0];
  const void* tag1_W = d_in[2];
  const void* tag1_b = d_in[3];
  const void* tag_W  = d_in[4];
  const void* tag_b  = d_in[5];
  const void* p1_W1  = d_in[6];
  const void* p1_b1  = d_in[7];
  const void* p1_W2  = d_in[8];
  const void* p1_b2  = d_in[9];
  const void* pf_W   = d_in[10];
  const void* pf_b   = d_in[11];
  const void* bn_g   = d_in[12];
  const void* bn_b   = d_in[13];
  const void* lin_W  = d_in[14];
  const void* lin_b  = d_in[15];
  const void* out_W  = d_in[16];
  const void* out_b  = d_in[17];

  // ---- workspace layout: total 10,485,776 floats ≈ 40 MB ----
  float* ws = (float*)d_ws;
  float* XF   = ws + 0;                 // 98304
  float* M16  = ws + 98304;             // 98304 (dead after proj3 C=6 -> reused as PP)
  float* M26  = ws + 196608;            // 98304
  float* Z    = ws + 294912;            // 49152
  float* ZB   = ws + 344064;            // 49152
  int*   FLAG = (int*)(ws + 409600);    // 16
  int*   NBRP = (int*)(ws + 409616);    // 49152 ints
  int*   NBRG = (int*)(ws + 458768);    // 1,638,400 ints -> ends 2,097,168
  float* S0   = ws + 2097168;           // 4 slots x 2,097,152 floats (8 MB each)
  float* S1   = ws + 4194320;           // S0+S1 contiguous -> 16 MB G region
  float* S2   = ws + 6291472;
  float* S3   = ws + 8388624;           // ends 10,485,776 floats
  float* PA   = S0;                     // head partials ping (589,824 floats)
  float* PB   = S1;                     // head partials pong
  float* PP   = M16;                    // pool partials (65536 floats)

  detect_kernel<<<1, 64, 0, stream>>>((const unsigned short*)x, FLAG);
  convert_kernel<<<384, 256, 0, stream>>>(x, XF, Bg * Nn * Fdim, FLAG);
  knn100_kernel<<<Bg * Nn / 4, 256, 0, stream>>>(XF, NBRG);
  knn3_x_kernel<<<Bg * Nn / 16, 256, 0, stream>>>(XF, NBRP);

  // ---- TAG branch ----
  gm6_kernel<<<Bg, 512, 0, stream>>>(XF, NBRG, M16);
  gm6_kernel<<<Bg, 512, 0, stream>>>(M16, NBRG, M26);
  proj3_kernel<<<2048, 128, 0, stream>>>(XF, M16, M26, tag1_W, tag1_b, S0, FLAG);
  pool1_kernel<<<256, 128, 0, stream>>>(S0, PP);
  pool2_kernel<<<Bg, 128, 0, stream>>>(PP, Z, 0, 128);

  gm128_kernel<<<Bg * Nn / 8, 256, 0, stream>>>(S0, NBRG, S1);
  gm128_kernel<<<Bg * Nn / 8, 256, 0, stream>>>(S1, NBRG, S2);
  proj3_big_kernel<<<512, 256, 0, stream>>>(S0, S1, S2, tag_W, tag_b, S3, 0, 0, FLAG);
  pool1_kernel<<<256, 128, 0, stream>>>(S3, PP);
  pool2_kernel<<<Bg, 128, 0, stream>>>(PP, Z, 256, 384);

  gm128_kernel<<<Bg * Nn / 8, 256, 0, stream>>>(S3, NBRG, S1);
  gm128_kernel<<<Bg * Nn / 8, 256, 0, stream>>>(S1, NBRG, S2);
  proj3_big_kernel<<<512, 256, 0, stream>>>(S3, S1, S2, tag_W, tag_b, S0,
                                            3L * 128 * 128, 128, FLAG);
  pool1_kernel<<<256, 128, 0, stream>>>(S0, PP);
  pool2_kernel<<<Bg, 128, 0, stream>>>(PP, Z, 512, 640);

  // ---- point branch ----
  proj_dual_kernel<<<2048, 128, 0, stream>>>(XF, p1_W1, S0, S1, FLAG);
  edge_mlp1_kernel<<<2048, 256, 0, stream>>>(S0, S1, NBRP, p1_W2, p1_b1, p1_b2, S2, FLAG);  // Y0=S2
  pool1_kernel<<<256, 128, 0, stream>>>(S2, PP);
  pool2_kernel<<<Bg, 128, 0, stream>>>(PP, Z, 768, 1152);

  for (int c = 0; c < Bg; c += GC16) {             // G=S0+S1 (U,V dead)
    gram_kernel<<<GC16 * 64, 256, 0, stream>>>(S2, S0, c);
    knn3_gram_kernel<<<GC16 * Nn / 16, 256, 0, stream>>>(S0, NBRP, c);
  }
  proj_dual_big_kernel<<<512, 256, 0, stream>>>(S2, pf_W, S0, S1, 0, FLAG);  // G dead
  edge_max_kernel<<<Bg * Nn, 128, 0, stream>>>(S0, S1, NBRP, pf_b, S3, 0, FLAG);  // Y1=S3
  pool1_kernel<<<256, 128, 0, stream>>>(S3, PP);
  pool2_kernel<<<Bg, 128, 0, stream>>>(PP, Z, 896, 1280);

  for (int c = 0; c < Bg; c += GC16) {             // G=S0+S1 (U,V dead)
    gram_kernel<<<GC16 * 64, 256, 0, stream>>>(S3, S0, c);
    knn3_gram_kernel<<<GC16 * Nn / 16, 256, 0, stream>>>(S0, NBRP, c);
  }
  proj_dual_big_kernel<<<512, 256, 0, stream>>>(S3, pf_W, S0, S1, 256L * 128, FLAG);  // G dead
  edge_max_kernel<<<Bg * Nn, 128, 0, stream>>>(S0, S1, NBRP, pf_b, S2, 128, FLAG);  // Y2=S2
  pool1_kernel<<<256, 128, 0, stream>>>(S2, PP);
  pool2_kernel<<<Bg, 128, 0, stream>>>(PP, Z, 1024, 1408);

  // ---- head: bn -> 5 x K-split linear (reduce fused into next stage) ----
  bn_kernel<<<6, 256, 0, stream>>>(Z, bn_g, bn_b, FLAG);
  hl_part_kernel<<<288, 256, 0, stream>>>(Z, nullptr, nullptr, lin_W, PA,
                                          0L * DIM2 * DIM2, 0L, 0, FLAG);
  hl_part_kernel<<<288, 256, 0, stream>>>(nullptr, PA, lin_b, lin_W, PB,
                                          1L * DIM2 * DIM2, 0L * DIM2, 1, FLAG);
  hl_part_kernel<<<288, 256, 0, stream>>>(nullptr, PB, lin_b, lin_W, PA,
                                          2L * DIM2 * DIM2, 1L * DIM2, 1, FLAG);
  hl_part_kernel<<<288, 256, 0, stream>>>(nullptr, PA, lin_b, lin_W, PB,
                                          3L * DIM2 * DIM2, 2L * DIM2, 1, FLAG);
  hl_part_kernel<<<288, 256, 0, stream>>>(nullptr, PB, lin_b, lin_W, PA,
                                          4L * DIM2 * DIM2, 3L * DIM2, 1, FLAG);
  hl_reduce_kernel<<<192, 256, 0, stream>>>(PA, lin_b, ZB, 4L * DIM2, FLAG);
  final_kernel<<<Bg, 256, 0, stream>>>(ZB, out_W, out_b, d_out, FLAG);
}

// Round 13
// 833.585 us; speedup vs baseline: 1.0309x; 1.0143x over previous
//
#include <hip/hip_runtime.h>
#include <hip/hip_bf16.h>

#define Bg 32
#define Nn 512
#define Fdim 6
#define Wd 128
#define KG 100
#define KP 3
#define DIM2 1536
#define GC16 16
#define NSL 12
#define KSL 128

typedef __hip_bfloat16 bf16;
typedef unsigned long long ull;

__device__ __forceinline__ float b2f(bf16 v) { return __bfloat162float(v); }
__device__ __forceinline__ float h2f(unsigned short h) { return __uint_as_float((unsigned)h << 16); }
__device__ __forceinline__ float lrelu(float v) { return v > 0.0f ? v : 0.01f * v; }

// ---------- dtype detection (f32=1 / bf16=0) ----------
__global__ void detect_kernel(const unsigned short* __restrict__ x, int* __restrict__ flag) {
  if (threadIdx.x == 0 && blockIdx.x == 0) {
    int big = 0;
    for (int i = 0; i < 512; i += 2) {
      unsigned short u = x[i];
      int e = (u >> 7) & 0xFF;
      if (e >= 140) big++;
    }
    *flag = (big > 20) ? 1 : 0;
  }
}

// ---------- convert x -> f32 ----------
__global__ void convert_kernel(const void* __restrict__ x, float* __restrict__ xf, int n,
                               const int* __restrict__ flag) {
  int i = blockIdx.x * 256 + threadIdx.x;
  if (i >= n) return;
  if (*flag) xf[i] = ((const float*)x)[i];
  else       xf[i] = b2f(((const bf16*)x)[i]);
}

// ---------- branchless sorted-3 insert ----------
__device__ __forceinline__ void ins3b(ull key, ull& k0, ull& k1, ull& k2) {
  ull M0 = k0 < key ? key : k0;  k0 = k0 < key ? k0 : key;
  ull M1 = k1 < M0 ? M0 : k1;    k1 = k1 < M0 ? k1 : M0;
  k2 = k2 < M1 ? k2 : M1;
}

// ---------- kNN k=100: one wave/row; ballot-popcount radix search ----------
__global__ void knn100_kernel(const float* __restrict__ xf, int* __restrict__ nbr) {
  __shared__ float xg[Nn * 7];
  __shared__ float sqv[Nn];
  int t = threadIdx.x; int w = t >> 6; int l = t & 63;
  int row0 = blockIdx.x * 4; int g = row0 >> 9;
  const float* xp = xf + g * (Nn * Fdim);
  for (int j = t; j < Nn; j += 256) {
    float s = 0.0f;
    #pragma unroll
    for (int c = 0; c < Fdim; c++) { float v = xp[j * Fdim + c]; xg[j * 7 + c] = v; s += v * v; }
    sqv[j] = s;
  }
  __syncthreads();
  int i = (row0 & 511) + w;
  float xi[Fdim];
  #pragma unroll
  for (int c = 0; c < Fdim; c++) xi[c] = xg[i * 7 + c];
  float sqi = sqv[i];
  unsigned m[8];
  #pragma unroll
  for (int ch = 0; ch < 8; ch++) {
    int j = ch * 64 + l;
    float dot = 0.0f;
    #pragma unroll
    for (int c = 0; c < Fdim; c++) dot += xi[c] * xg[j * 7 + c];
    float d = sqi + sqv[j] - 2.0f * dot;
    if (j == i) d += 1e10f;
    unsigned u = __float_as_uint(d);
    m[ch] = (u & 0x80000000u) ? ~u : (u | 0x80000000u);
  }
  unsigned T = 0u;
  for (int b = 31; b >= 0; b--) {
    unsigned mid = T | (1u << b);
    int c = 0;
    #pragma unroll
    for (int ch = 0; ch < 8; ch++) c += __popcll(__ballot(m[ch] < mid));
    if (c < KG) T = mid;
  }
  int* outp = nbr + ((size_t)(g * Nn + i)) * KG;
  ull lmask = (1ull << l) - 1ull;
  int base = 0;
  #pragma unroll
  for (int ch = 0; ch < 8; ch++) {
    bool less = m[ch] < T;
    ull bal = __ballot(less);
    if (less) outp[base + __popcll(bal & lmask)] = ch * 64 + l;
    base += __popcll(bal);
  }
  int need = KG - base;
  int eqb = 0;
  #pragma unroll
  for (int ch = 0; ch < 8; ch++) {
    bool eq = (m[ch] == T);
    ull bal = __ballot(eq);
    int gr = eqb + __popcll(bal & lmask);
    if (eq && gr < need) outp[base + gr] = ch * 64 + l;
    eqb += __popcll(bal);
  }
}

// ---------- kNN k=3 on coords: 16 lanes/row ----------
__global__ void knn3_x_kernel(const float* __restrict__ xf, int* __restrict__ nbr) {
  __shared__ float xg[Nn * 7];
  __shared__ float sqv[Nn];
  int t = threadIdx.x; int bid = blockIdx.x;
  int g = bid >> 5;
  const float* xp = xf + g * (Nn * Fdim);
  for (int j = t; j < Nn; j += 256) {
    float s = 0.0f;
    #pragma unroll
    for (int c = 0; c < Fdim; c++) { float v = xp[j * Fdim + c]; xg[j * 7 + c] = v; s += v * v; }
    sqv[j] = s;
  }
  __syncthreads();
  int lr = t >> 4; int sub = t & 15; int l = t & 63;
  int i = ((bid & 31) << 4) + lr;
  float xi[Fdim];
  #pragma unroll
  for (int c = 0; c < Fdim; c++) xi[c] = xg[i * 7 + c];
  float sqi = sqv[i];
  ull k0 = ~0ull, k1 = ~0ull, k2 = ~0ull;
  for (int jj = 0; jj < 32; jj++) {
    int s = (jj + l) & 31;
    int j = sub * 32 + s;
    float dot = 0.0f;
    #pragma unroll
    for (int c = 0; c < Fdim; c++) dot += xi[c] * xg[j * 7 + c];
    float d = sqi + sqv[j] - 2.0f * dot;
    if (j == i) d += 1e10f;
    unsigned u = __float_as_uint(d);
    unsigned m = (u & 0x80000000u) ? ~u : (u | 0x80000000u);
    ins3b(((ull)m << 32) | (unsigned)j, k0, k1, k2);
  }
  #pragma unroll
  for (int off = 1; off <= 8; off <<= 1) {
    ull b0 = __shfl_xor(k0, off, 64);
    ull b1 = __shfl_xor(k1, off, 64);
    ull b2 = __shfl_xor(k2, off, 64);
    ins3b(b0, k0, k1, k2); ins3b(b1, k0, k1, k2); ins3b(b2, k0, k1, k2);
  }
  if (sub == 0) {
    int row = g * Nn + i;
    nbr[row * 3 + 0] = (int)(k0 & 0xFFFFFFFFu);
    nbr[row * 3 + 1] = (int)(k1 & 0xFFFFFFFFu);
    nbr[row * 3 + 2] = (int)(k2 & 0xFFFFFFFFu);
  }
}

// ---------- kNN k=3 from chunked Gram ----------
__global__ void knn3_gram_kernel(const float* __restrict__ G, int* __restrict__ nbr, int g0) {
  __shared__ float sqv[Nn];
  int t = threadIdx.x; int bid = blockIdx.x;
  int gl = bid >> 5; int g = g0 + gl;
  const float* Gg = G + (size_t)gl * Nn * Nn;
  for (int j = t; j < Nn; j += 256) sqv[j] = Gg[(size_t)j * Nn + j];
  __syncthreads();
  int lr = t >> 4; int sub = t & 15; int l = t & 63;
  int i = ((bid & 31) << 4) + lr;
  float sqi = sqv[i];
  const float* Gr = Gg + (size_t)i * Nn;
  ull k0 = ~0ull, k1 = ~0ull, k2 = ~0ull;
  for (int jj = 0; jj < 32; jj++) {
    int s = (jj + l) & 31;
    int j = sub * 32 + s;
    float d = sqi + sqv[j] - 2.0f * Gr[j];
    if (j == i) d += 1e10f;
    unsigned u = __float_as_uint(d);
    unsigned m = (u & 0x80000000u) ? ~u : (u | 0x80000000u);
    ins3b(((ull)m << 32) | (unsigned)j, k0, k1, k2);
  }
  #pragma unroll
  for (int off = 1; off <= 8; off <<= 1) {
    ull b0 = __shfl_xor(k0, off, 64);
    ull b1 = __shfl_xor(k1, off, 64);
    ull b2 = __shfl_xor(k2, off, 64);
    ins3b(b0, k0, k1, k2); ins3b(b1, k0, k1, k2); ins3b(b2, k0, k1, k2);
  }
  if (sub == 0) {
    int row = g * Nn + i;
    nbr[row * 3 + 0] = (int)(k0 & 0xFFFFFFFFu);
    nbr[row * 3 + 1] = (int)(k1 & 0xFFFFFFFFu);
    nbr[row * 3 + 2] = (int)(k2 & 0xFFFFFFFFu);
  }
}

// ---------- neighbor-mean over 100, C=6 ----------
__global__ void gm6_kernel(const float* __restrict__ src, const int* __restrict__ nbr,
                           float* __restrict__ dst) {
  __shared__ float s[Nn * Fdim];
  int g = blockIdx.x; int t = threadIdx.x;  // 512
  const float* sp = src + g * (Nn * Fdim);
  for (int idx = t; idx < Nn * Fdim; idx += 512) s[idx] = sp[idx];
  __syncthreads();
  float acc[Fdim] = {0, 0, 0, 0, 0, 0};
  const int* nb = nbr + ((size_t)(g * Nn + t)) * KG;
  for (int k = 0; k < KG; k++) {
    int j = nb[k];
    #pragma unroll
    for (int c = 0; c < Fdim; c++) acc[c] += s[j * Fdim + c];
  }
  float* dp = dst + (size_t)(g * Nn + t) * Fdim;
  #pragma unroll
  for (int c = 0; c < Fdim; c++) dp[c] = acc[c] / 100.0f;
}

// ---------- neighbor-mean over 100, C=128: 8 rows/block, float4 gathers ----------
__global__ void gm128_kernel(const float* __restrict__ src, const int* __restrict__ nbr,
                             float* __restrict__ dst) {
  __shared__ int ids[8][KG];
  int t = threadIdx.x;  // 256
  int row0 = blockIdx.x * 8; int g = row0 >> 9;
  for (int idx = t; idx < 8 * KG; idx += 256) {
    int r = idx / KG, k = idx - r * KG;
    ids[r][k] = nbr[(size_t)(row0 + r) * KG + k];
  }
  __syncthreads();
  int lane = t & 31, r = t >> 5;  // r in 0..7
  const float4* sp = (const float4*)(src + (size_t)g * Nn * Wd);
  float ax = 0.0f, ay = 0.0f, az = 0.0f, aw = 0.0f;
  #pragma unroll 5
  for (int k = 0; k < KG; k++) {
    float4 v = sp[ids[r][k] * 32 + lane];
    ax += v.x; ay += v.y; az += v.z; aw += v.w;
  }
  float4 o = make_float4(ax / 100.0f, ay / 100.0f, az / 100.0f, aw / 100.0f);
  ((float4*)(dst + (size_t)(row0 + r) * Wd))[lane] = o;
}

// ---------- proj3 small (C=6 only; proven r10 path) ----------
__global__ void proj3_kernel(const float* __restrict__ in0, const float* __restrict__ in1,
                             const float* __restrict__ in2, const void* __restrict__ Wt_,
                             const void* __restrict__ bt_, float* __restrict__ out,
                             const int* __restrict__ flag) {
  __shared__ float s0[48], s1[48], s2[48];
  int t = threadIdx.x;  // 128
  int node0 = blockIdx.x * 8;
  int f32 = *flag;
  float acc[8] = {0, 0, 0, 0, 0, 0, 0, 0};
  float bd;
  if (t < 48) {
    s0[t] = in0[(size_t)node0 * 6 + t];
    s1[t] = in1[(size_t)node0 * 6 + t];
    s2[t] = in2[(size_t)node0 * 6 + t];
  }
  __syncthreads();
  if (f32) {
    const float* W = (const float*)Wt_;
    for (int c = 0; c < 6; c++) {
      float w0 = W[c * 128 + t], w1 = W[(6 + c) * 128 + t], w2 = W[(12 + c) * 128 + t];
      #pragma unroll
      for (int n = 0; n < 8; n++)
        acc[n] += s0[n * 6 + c] * w0 + s1[n * 6 + c] * w1 + s2[n * 6 + c] * w2;
    }
    bd = ((const float*)bt_)[t];
  } else {
    const bf16* W = (const bf16*)Wt_;
    for (int c = 0; c < 6; c++) {
      float w0 = b2f(W[c * 128 + t]), w1 = b2f(W[(6 + c) * 128 + t]), w2 = b2f(W[(12 + c) * 128 + t]);
      #pragma unroll
      for (int n = 0; n < 8; n++)
        acc[n] += s0[n * 6 + c] * w0 + s1[n * 6 + c] * w1 + s2[n * 6 + c] * w2;
    }
    bd = b2f(((const bf16*)bt_)[t]);
  }
  #pragma unroll
  for (int n = 0; n < 8; n++)
    out[(size_t)(node0 + n) * 128 + t] = lrelu(acc[n] + bd);
}

// ---------- proj3 big (C=128): chunk-staged W in LDS (64 rows, single-buffered) ----------
__global__ void proj3_big_kernel(const float* __restrict__ in0, const float* __restrict__ in1,
                                 const float* __restrict__ in2, const void* __restrict__ Wt_,
                                 const void* __restrict__ bt_, float* __restrict__ out,
                                 long Woff, long boff, const int* __restrict__ flag) {
  __shared__ __align__(16) float sa[3][32 * 128];  // 48 KB
  __shared__ __align__(16) float Wc[64 * 128];     // 32 KB chunk
  int t = threadIdx.x;  // 256
  int node0 = blockIdx.x * 32;
  int f32 = *flag;
  // ---- stage inputs ----
  {
    const float4* q0 = (const float4*)(in0 + (size_t)node0 * 128);
    const float4* q1 = (const float4*)(in1 + (size_t)node0 * 128);
    const float4* q2 = (const float4*)(in2 + (size_t)node0 * 128);
    float4* s0 = (float4*)sa[0]; float4* s1 = (float4*)sa[1]; float4* s2 = (float4*)sa[2];
    #pragma unroll
    for (int it = 0; it < 4; it++) {
      s0[t + it * 256] = q0[t + it * 256];
      s1[t + it * 256] = q1[t + it * 256];
      s2[t + it * 256] = q2[t + it * 256];
    }
  }
  int tx = t & 31, ty = t >> 5;
  int col0 = tx * 4, n0 = ty * 4;
  float acc[4][4];
  #pragma unroll
  for (int n = 0; n < 4; n++)
    #pragma unroll
    for (int j = 0; j < 4; j++) acc[n][j] = 0.0f;
  for (int half = 0; half < 6; half++) {   // a = half>>1, 64-row half h = half&1
    int a = half >> 1, h = half & 1;
    {
      float4* Wl = (float4*)Wc;
      if (f32) {
        const float4* Wg = (const float4*)((const float*)Wt_ + Woff
                                           + (size_t)a * 16384 + (size_t)h * 8192);
        #pragma unroll
        for (int i = 0; i < 8; i++) Wl[t + i * 256] = Wg[t + i * 256];
      } else {
        const ushort4* Wg = (const ushort4*)((const unsigned short*)Wt_ + Woff
                                             + (size_t)a * 16384 + (size_t)h * 8192);
        #pragma unroll
        for (int i = 0; i < 8; i++) {
          ushort4 hh = Wg[t + i * 256];
          Wl[t + i * 256] = make_float4(h2f(hh.x), h2f(hh.y), h2f(hh.z), h2f(hh.w));
        }
      }
    }
    __syncthreads();   // chunk (and, on half=0, inputs) visible
    const float* sp = sa[a];
    int cbase = h * 64;
    #pragma unroll 4
    for (int cc0 = 0; cc0 < 64; cc0 += 4) {
      float wv[4][4];
      #pragma unroll
      for (int cc = 0; cc < 4; cc++) {
        float4 w4 = *(const float4*)&Wc[(cc0 + cc) * 128 + col0];
        wv[cc][0] = w4.x; wv[cc][1] = w4.y; wv[cc][2] = w4.z; wv[cc][3] = w4.w;
      }
      int c0 = cbase + cc0;
      #pragma unroll
      for (int n = 0; n < 4; n++) {
        float4 av = *(const float4*)&sp[(n0 + n) * 128 + c0];
        #pragma unroll
        for (int j = 0; j < 4; j++)
          acc[n][j] += av.x * wv[0][j] + av.y * wv[1][j] + av.z * wv[2][j] + av.w * wv[3][j];
      }
    }
    __syncthreads();   // protect Wc before next stage
  }
  float bdv[4];
  if (f32) {
    const float* bt = (const float*)bt_ + boff;
    #pragma unroll
    for (int j = 0; j < 4; j++) bdv[j] = bt[col0 + j];
  } else {
    const bf16* bt = (const bf16*)bt_ + boff;
    #pragma unroll
    for (int j = 0; j < 4; j++) bdv[j] = b2f(bt[col0 + j]);
  }
  #pragma unroll
  for (int n = 0; n < 4; n++) {
    float4 ov;
    ov.x = lrelu(acc[n][0] + bdv[0]); ov.y = lrelu(acc[n][1] + bdv[1]);
    ov.z = lrelu(acc[n][2] + bdv[2]); ov.w = lrelu(acc[n][3] + bdv[3]);
    *(float4*)&out[(size_t)(node0 + n0 + n) * 128 + col0] = ov;
  }
}

// ---------- proj_dual small (C=6 only; proven r10 path) ----------
__global__ void proj_dual_kernel(const float* __restrict__ in, const void* __restrict__ Wt_,
                                 float* __restrict__ u, float* __restrict__ v,
                                 const int* __restrict__ flag) {
  __shared__ float s0[48];
  int t = threadIdx.x; int node0 = blockIdx.x * 8;
  int f32 = *flag;
  float au[8] = {0, 0, 0, 0, 0, 0, 0, 0};
  float av[8] = {0, 0, 0, 0, 0, 0, 0, 0};
  if (t < 48) s0[t] = in[(size_t)node0 * 6 + t];
  __syncthreads();
  if (f32) {
    const float* W = (const float*)Wt_;
    for (int c = 0; c < 6; c++) {
      float wa = W[c * 128 + t], wb = W[(6 + c) * 128 + t];
      #pragma unroll
      for (int n = 0; n < 8; n++) { float x = s0[n * 6 + c]; au[n] += x * wa; av[n] += x * wb; }
    }
  } else {
    const bf16* W = (const bf16*)Wt_;
    for (int c = 0; c < 6; c++) {
      float wa = b2f(W[c * 128 + t]), wb = b2f(W[(6 + c) * 128 + t]);
      #pragma unroll
      for (int n = 0; n < 8; n++) { float x = s0[n * 6 + c]; au[n] += x * wa; av[n] += x * wb; }
    }
  }
  #pragma unroll
  for (int n = 0; n < 8; n++) {
    u[(size_t)(node0 + n) * 128 + t] = au[n];
    v[(size_t)(node0 + n) * 128 + t] = av[n];
  }
}

// ---------- proj_dual big (C=128): chunk-staged W in LDS (4 x 64-row chunks) ----------
__global__ void proj_dual_big_kernel(const float* __restrict__ in, const void* __restrict__ Wt_,
                                     float* __restrict__ u, float* __restrict__ v,
                                     long Woff, const int* __restrict__ flag) {
  __shared__ __align__(16) float sa[32 * 128];     // 16 KB
  __shared__ __align__(16) float Wc[64 * 128];     // 32 KB chunk
  int t = threadIdx.x;  // 256
  int node0 = blockIdx.x * 32;
  int f32 = *flag;
  {
    const float4* qp = (const float4*)(in + (size_t)node0 * 128);
    float4* s0 = (float4*)sa;
    #pragma unroll
    for (int it = 0; it < 4; it++) s0[t + it * 256] = qp[t + it * 256];
  }
  int tx = t & 31, ty = t >> 5;
  int col0 = tx * 4, n0 = ty * 4;
  float accu[4][4], accv[4][4];
  #pragma unroll
  for (int n = 0; n < 4; n++)
    #pragma unroll
    for (int j = 0; j < 4; j++) { accu[n][j] = 0.0f; accv[n][j] = 0.0f; }
  for (int q = 0; q < 4; q++) {
    {
      float4* Wl = (float4*)Wc;
      if (f32) {
        const float4* Wg = (const float4*)((const float*)Wt_ + Woff + (size_t)q * 8192);
        #pragma unroll
        for (int i = 0; i < 8; i++) Wl[t + i * 256] = Wg[t + i * 256];
      } else {
        const ushort4* Wg = (const ushort4*)((const unsigned short*)Wt_ + Woff
                                             + (size_t)q * 8192);
        #pragma unroll
        for (int i = 0; i < 8; i++) {
          ushort4 hh = Wg[t + i * 256];
          Wl[t + i * 256] = make_float4(h2f(hh.x), h2f(hh.y), h2f(hh.z), h2f(hh.w));
        }
      }
    }
    __syncthreads();
    int cbase = (q & 1) * 64;
    if (q < 2) {
      #pragma unroll 4
      for (int cc0 = 0; cc0 < 64; cc0 += 4) {
        float wv[4][4];
        #pragma unroll
        for (int cc = 0; cc < 4; cc++) {
          float4 w4 = *(const float4*)&Wc[(cc0 + cc) * 128 + col0];
          wv[cc][0] = w4.x; wv[cc][1] = w4.y; wv[cc][2] = w4.z; wv[cc][3] = w4.w;
        }
        int c0 = cbase + cc0;
        #pragma unroll
        for (int n = 0; n < 4; n++) {
          float4 av = *(const float4*)&sa[(n0 + n) * 128 + c0];
          #pragma unroll
          for (int j = 0; j < 4; j++)
            accu[n][j] += av.x * wv[0][j] + av.y * wv[1][j] + av.z * wv[2][j] + av.w * wv[3][j];
        }
      }
    } else {
      #pragma unroll 4
      for (int cc0 = 0; cc0 < 64; cc0 += 4) {
        float wv[4][4];
        #pragma unroll
        for (int cc = 0; cc < 4; cc++) {
          float4 w4 = *(const float4*)&Wc[(cc0 + cc) * 128 + col0];
          wv[cc][0] = w4.x; wv[cc][1] = w4.y; wv[cc][2] = w4.z; wv[cc][3] = w4.w;
        }
        int c0 = cbase + cc0;
        #pragma unroll
        for (int n = 0; n < 4; n++) {
          float4 av = *(const float4*)&sa[(n0 + n) * 128 + c0];
          #pragma unroll
          for (int j = 0; j < 4; j++)
            accv[n][j] += av.x * wv[0][j] + av.y * wv[1][j] + av.z * wv[2][j] + av.w * wv[3][j];
        }
      }
    }
    __syncthreads();
  }
  #pragma unroll
  for (int n = 0; n < 4; n++) {
    *(float4*)&u[(size_t)(node0 + n0 + n) * 128 + col0] = *(float4*)accu[n];
    *(float4*)&v[(size_t)(node0 + n0 + n) * 128 + col0] = *(float4*)accv[n];
  }
}

// ---------- edgeconv1: half-W LDS staging (2 x 32 KB), single-buffered ----------
// r11 post-mortem: 6x8/32-node tile arc (r9-r11) all landed >=51 us vs this
// variant's ~43-47 us -- occupancy/latency dominates, not LDS reads. PARKED.
__global__ void edge_mlp1_kernel(const float* __restrict__ u, const float* __restrict__ v,
                                 const int* __restrict__ nbrp, const void* __restrict__ W2_,
                                 const void* __restrict__ b1_, const void* __restrict__ b2_,
                                 float* __restrict__ y, const int* __restrict__ flag) {
  __shared__ __align__(16) float Ws[64 * 128];  // 32 KB (one half of W)
  __shared__ __align__(16) float tl[24][128];   // 12 KB
  int t = threadIdx.x;  // 256
  int node0 = blockIdx.x * 8; int g = node0 >> 9;
  int f32 = *flag;
  // ---- stage W half 0 (K-rows 0..63) ----
  if (f32) {
    const float4* Wg = (const float4*)W2_;
    float4* Wl = (float4*)Ws;
    #pragma unroll
    for (int i = 0; i < 8; i++) Wl[t + i * 256] = Wg[t + i * 256];
  } else {
    const ushort4* Wg = (const ushort4*)W2_;
    float4* Wl = (float4*)Ws;
    #pragma unroll
    for (int i = 0; i < 8; i++) {
      ushort4 h = Wg[t + i * 256];
      Wl[t + i * 256] = make_float4(h2f(h.x), h2f(h.y), h2f(h.z), h2f(h.w));
    }
  }
  // ---- phase 1: group n = t>>5 builds tl rows 3n..3n+2 via float4 ----
  {
    int lane = t & 31, n = t >> 5;
    int row = node0 + n;
    float4 ui = ((const float4*)(u + (size_t)row * 128))[lane];
    float4 vi = ((const float4*)(v + (size_t)row * 128))[lane];
    float4 b1v;
    if (f32) b1v = ((const float4*)b1_)[lane];
    else {
      ushort4 h = ((const ushort4*)b1_)[lane];
      b1v = make_float4(h2f(h.x), h2f(h.y), h2f(h.z), h2f(h.w));
    }
    float4 base = make_float4(ui.x - vi.x + b1v.x, ui.y - vi.y + b1v.y,
                              ui.z - vi.z + b1v.z, ui.w - vi.w + b1v.w);
    #pragma unroll
    for (int k = 0; k < 3; k++) {
      int j = nbrp[row * 3 + k];
      float4 vj = ((const float4*)(v + (size_t)(g * Nn + j) * 128))[lane];
      float4 tv;
      tv.x = lrelu(base.x + vj.x); tv.y = lrelu(base.y + vj.y);
      tv.z = lrelu(base.z + vj.z); tv.w = lrelu(base.w + vj.w);
      *(float4*)&tl[n * 3 + k][lane * 4] = tv;
    }
  }
  __syncthreads();
  int tx = t & 31, ty = t >> 5;
  int col0 = tx * 4;
  float acc[3][4];
  #pragma unroll
  for (int k = 0; k < 3; k++)
    #pragma unroll
    for (int j = 0; j < 4; j++) acc[k][j] = 0.0f;
  // ---- compute half 0 (K = 0..63) ----
  #pragma unroll 4
  for (int cc0 = 0; cc0 < 64; cc0 += 4) {
    float wv[4][4];
    #pragma unroll
    for (int cc = 0; cc < 4; cc++) {
      float4 w4 = *(const float4*)&Ws[(cc0 + cc) * 128 + col0];
      wv[cc][0] = w4.x; wv[cc][1] = w4.y; wv[cc][2] = w4.z; wv[cc][3] = w4.w;
    }
    #pragma unroll
    for (int k = 0; k < 3; k++) {
      float4 av = *(const float4*)&tl[ty * 3 + k][cc0];
      #pragma unroll
      for (int j = 0; j < 4; j++)
        acc[k][j] += av.x * wv[0][j] + av.y * wv[1][j] + av.z * wv[2][j] + av.w * wv[3][j];
    }
  }
  __syncthreads();
  // ---- stage W half 1 (K-rows 64..127) ----
  if (f32) {
    const float4* Wg = (const float4*)W2_ + 2048;
    float4* Wl = (float4*)Ws;
    #pragma unroll
    for (int i = 0; i < 8; i++) Wl[t + i * 256] = Wg[t + i * 256];
  } else {
    const ushort4* Wg = (const ushort4*)W2_ + 2048;
    float4* Wl = (float4*)Ws;
    #pragma unroll
    for (int i = 0; i < 8; i++) {
      ushort4 h = Wg[t + i * 256];
      Wl[t + i * 256] = make_float4(h2f(h.x), h2f(h.y), h2f(h.z), h2f(h.w));
    }
  }
  __syncthreads();
  // ---- compute half 1 (K = 64..127) ----
  #pragma unroll 4
  for (int cc0 = 0; cc0 < 64; cc0 += 4) {
    float wv[4][4];
    #pragma unroll
    for (int cc = 0; cc < 4; cc++) {
      float4 w4 = *(const float4*)&Ws[(cc0 + cc) * 128 + col0];
      wv[cc][0] = w4.x; wv[cc][1] = w4.y; wv[cc][2] = w4.z; wv[cc][3] = w4.w;
    }
    #pragma unroll
    for (int k = 0; k < 3; k++) {
      float4 av = *(const float4*)&tl[ty * 3 + k][64 + cc0];
      #pragma unroll
      for (int j = 0; j < 4; j++)
        acc[k][j] += av.x * wv[0][j] + av.y * wv[1][j] + av.z * wv[2][j] + av.w * wv[3][j];
    }
  }
  float b2d[4];
  if (f32) {
    const float* b2p = (const float*)b2_;
    #pragma unroll
    for (int j = 0; j < 4; j++) b2d[j] = b2p[col0 + j];
  } else {
    const bf16* b2p = (const bf16*)b2_;
    #pragma unroll
    for (int j = 0; j < 4; j++) b2d[j] = b2f(b2p[col0 + j]);
  }
  float4 ov;
  {
    float m0 = lrelu(acc[0][0] + b2d[0]);
    m0 = fmaxf(m0, lrelu(acc[1][0] + b2d[0]));
    ov.x = fmaxf(m0, lrelu(acc[2][0] + b2d[0]));
    float m1 = lrelu(acc[0][1] + b2d[1]);
    m1 = fmaxf(m1, lrelu(acc[1][1] + b2d[1]));
    ov.y = fmaxf(m1, lrelu(acc[2][1] + b2d[1]));
    float m2 = lrelu(acc[0][2] + b2d[2]);
    m2 = fmaxf(m2, lrelu(acc[1][2] + b2d[2]));
    ov.z = fmaxf(m2, lrelu(acc[2][2] + b2d[2]));
    float m3 = lrelu(acc[0][3] + b2d[3]);
    m3 = fmaxf(m3, lrelu(acc[1][3] + b2d[3]));
    ov.w = fmaxf(m3, lrelu(acc[2][3] + b2d[3]));
  }
  *(float4*)&y[(size_t)(node0 + ty) * 128 + col0] = ov;
}

// ---------- edgeconv2/3 ----------
__global__ void edge_max_kernel(const float* __restrict__ u, const float* __restrict__ v,
                                const int* __restrict__ nbrp, const void* __restrict__ bias_,
                                float* __restrict__ y, long boff, const int* __restrict__ flag) {
  int row = blockIdx.x; int g = row >> 9; int t = threadIdx.x;  // 128
  float ui = u[(size_t)row * 128 + t], vi = v[(size_t)row * 128 + t];
  float bd;
  if (*flag) bd = ((const float*)bias_ + boff)[t]; else bd = b2f(((const bf16*)bias_ + boff)[t]);
  float m = -3.4e38f;
  #pragma unroll
  for (int k = 0; k < 3; k++) {
    int j = nbrp[row * 3 + k];
    m = fmaxf(m, lrelu(ui - vi + v[(size_t)(g * Nn + j) * 128 + t] + bd));
  }
  y[(size_t)row * 128 + t] = m;
}

// ---------- chunked Gram matrix: transposed LDS tiles + float4 reads ----------
// r13: old layout As[64][17] forced 8 scalar ds_read_b32 per kk (column access,
// stride 17) -> 1024 b32/thread/dispatch, LDS-issue bound (~5.9K cyc/wave vs
// 4.1K FMA). New: At[kk][row] (pad 68 keeps 16B alignment; bank aliasing
// <=2-way = free) -> 2 ds_read_b128 per kk (At broadcast, Bt contiguous) and
// float4 global staging. LDS instr /4, same LDS size, same output indexing.
__global__ void gram_kernel(const float* __restrict__ y, float* __restrict__ G, int g0) {
  __shared__ float At[16][68], Bt[16][68];
  int bid = blockIdx.x;
  int gl = bid >> 6; int tt = bid & 63; int ti = tt >> 3; int tj = tt & 7;
  int g = g0 + gl;
  int t = threadIdx.x; int tx = t & 15, ty = t >> 4;
  const float* Yg = y + (size_t)g * Nn * Wd;
  float* Gg = G + (size_t)gl * Nn * Nn;
  int sr = t >> 2, sq = (t & 3) * 4;   // staging: row 0..63, col-quad
  float c[4][4];
  #pragma unroll
  for (int p = 0; p < 4; p++)
    #pragma unroll
    for (int q = 0; q < 4; q++) c[p][q] = 0.0f;
  for (int k0 = 0; k0 < 128; k0 += 16) {
    {
      float4 a4 = *(const float4*)&Yg[(ti * 64 + sr) * 128 + k0 + sq];
      float4 b4 = *(const float4*)&Yg[(tj * 64 + sr) * 128 + k0 + sq];
      At[sq + 0][sr] = a4.x; At[sq + 1][sr] = a4.y; At[sq + 2][sr] = a4.z; At[sq + 3][sr] = a4.w;
      Bt[sq + 0][sr] = b4.x; Bt[sq + 1][sr] = b4.y; Bt[sq + 2][sr] = b4.z; Bt[sq + 3][sr] = b4.w;
    }
    __syncthreads();
    #pragma unroll 4
    for (int kk = 0; kk < 16; kk++) {
      float4 a4 = *(const float4*)&At[kk][ty * 4];
      float4 b4 = *(const float4*)&Bt[kk][tx * 4];
      float a[4] = {a4.x, a4.y, a4.z, a4.w};
      float bb[4] = {b4.x, b4.y, b4.z, b4.w};
      #pragma unroll
      for (int p = 0; p < 4; p++)
        #pragma unroll
        for (int q = 0; q < 4; q++) c[p][q] += a[p] * bb[q];
    }
    __syncthreads();
  }
  #pragma unroll
  for (int p = 0; p < 4; p++)
    #pragma unroll
    for (int q = 0; q < 4; q++)
      Gg[(size_t)(ti * 64 + ty * 4 + p) * Nn + tj * 64 + tx * 4 + q] = c[p][q];
}

// ---------- two-pass mean+max pool ----------
__global__ void pool1_kernel(const float* __restrict__ h, float* __restrict__ pp) {
  int b = blockIdx.x;                 // 256: g*8 + chunk
  int g = b >> 3, ch = b & 7;
  int t = threadIdx.x;                // 128
  const float* hg = h + (size_t)g * Nn * Wd + (size_t)ch * 64 * Wd;
  float s = 0.0f, m = -3.4e38f;
  #pragma unroll 4
  for (int n = 0; n < 64; n++) {
    float vv = hg[n * 128 + t];
    s += vv; m = fmaxf(m, vv);
  }
  pp[b * 256 + t] = s;
  pp[b * 256 + 128 + t] = m;
}

__global__ void pool2_kernel(const float* __restrict__ pp, float* __restrict__ z,
                             int meanoff, int maxoff) {
  int g = blockIdx.x; int t = threadIdx.x;  // 128
  float s = 0.0f, m = -3.4e38f;
  #pragma unroll
  for (int q = 0; q < 8; q++) {
    s += pp[(g * 8 + q) * 256 + t];
    m = fmaxf(m, pp[(g * 8 + q) * 256 + 128 + t]);
  }
  z[g * DIM2 + meanoff + t] = s / 512.0f;
  z[g * DIM2 + maxoff + t] = m;
}

// ---------- BatchNorm1d (batch stats), in place ----------
__global__ void bn_kernel(float* __restrict__ z, const void* __restrict__ gamma,
                          const void* __restrict__ beta, const int* __restrict__ flag) {
  int c = blockIdx.x * 256 + threadIdx.x;
  if (c >= DIM2) return;
  float s = 0.0f;
  for (int r = 0; r < Bg; r++) s += z[r * DIM2 + c];
  float mu = s / 32.0f;
  float v = 0.0f;
  for (int r = 0; r < Bg; r++) { float d = z[r * DIM2 + c] - mu; v += d * d; }
  float var = v / 32.0f;
  float gm, bt;
  if (*flag) { gm = ((const float*)gamma)[c]; bt = ((const float*)beta)[c]; }
  else       { gm = b2f(((const bf16*)gamma)[c]); bt = b2f(((const bf16*)beta)[c]); }
  float scale = gm / sqrtf(var + 1e-5f);
  for (int r = 0; r < Bg; r++) z[r * DIM2 + c] = (z[r * DIM2 + c] - mu) * scale + bt;
}

// ---------- head linear, K-split partial GEMM (no transpose) ----------
__global__ void hl_part_kernel(const float* __restrict__ zin, const float* __restrict__ Pin,
                               const void* __restrict__ bin_, const void* __restrict__ W_,
                               float* __restrict__ Pout, long Woff, long binoff, int mode,
                               const int* __restrict__ flag) {
  __shared__ __align__(16) float zs[32][KSL];  // 16 KB
  int t = threadIdx.x;  // 256
  int bd = blockIdx.x % 24, s = blockIdx.x / 24;
  int d0 = bd * 64, k0 = s * KSL;
  int f32 = *flag;
  if (mode == 0) {
    for (int idx = t; idx < 32 * KSL; idx += 256) {
      int r = idx >> 7, k = idx & 127;
      zs[r][k] = zin[r * DIM2 + k0 + k];
    }
  } else {
    // z[r][k] = lrelu(sum_s Pin[r][s][k0+k] + b[k0+k])
    for (int idx = t; idx < 32 * KSL / 4; idx += 256) {
      int r = idx >> 5, k4 = (idx & 31) * 4;
      float ax = 0.0f, ay = 0.0f, az = 0.0f, aw = 0.0f;
      const float* Pr = Pin + (size_t)r * NSL * DIM2 + k0 + k4;
      #pragma unroll
      for (int ss = 0; ss < NSL; ss++) {
        float4 p = *(const float4*)(Pr + (size_t)ss * DIM2);
        ax += p.x; ay += p.y; az += p.z; aw += p.w;
      }
      float b0, b1, b2, b3;
      if (f32) {
        const float* bp = (const float*)bin_ + binoff + k0 + k4;
        b0 = bp[0]; b1 = bp[1]; b2 = bp[2]; b3 = bp[3];
      } else {
        const bf16* bp = (const bf16*)bin_ + binoff + k0 + k4;
        b0 = b2f(bp[0]); b1 = b2f(bp[1]); b2 = b2f(bp[2]); b3 = b2f(bp[3]);
      }
      zs[r][k4 + 0] = lrelu(ax + b0);
      zs[r][k4 + 1] = lrelu(ay + b1);
      zs[r][k4 + 2] = lrelu(az + b2);
      zs[r][k4 + 3] = lrelu(aw + b3);
    }
  }
  __syncthreads();
  int lane = t & 63, rg = t >> 6;  // 64 cols per wave; 4 rowgroups of 8 rows
  int d = d0 + lane, r0 = rg * 8;
  float acc[8];
  #pragma unroll
  for (int i = 0; i < 8; i++) acc[i] = 0.0f;
  if (f32) {
    const float* W = (const float*)W_ + Woff;
    for (int k = 0; k < KSL; k += 4) {
      float w0 = W[(size_t)(k0 + k) * DIM2 + d];
      float w1 = W[(size_t)(k0 + k + 1) * DIM2 + d];
      float w2 = W[(size_t)(k0 + k + 2) * DIM2 + d];
      float w3 = W[(size_t)(k0 + k + 3) * DIM2 + d];
      #pragma unroll
      for (int i = 0; i < 8; i++) {
        float4 z4 = *(const float4*)&zs[r0 + i][k];
        acc[i] += z4.x * w0 + z4.y * w1 + z4.z * w2 + z4.w * w3;
      }
    }
  } else {
    const unsigned short* W = (const unsigned short*)W_ + Woff;
    for (int k = 0; k < KSL; k += 4) {
      float w0 = h2f(W[(size_t)(k0 + k) * DIM2 + d]);
      float w1 = h2f(W[(size_t)(k0 + k + 1) * DIM2 + d]);
      float w2 = h2f(W[(size_t)(k0 + k + 2) * DIM2 + d]);
      float w3 = h2f(W[(size_t)(k0 + k + 3) * DIM2 + d]);
      #pragma unroll
      for (int i = 0; i < 8; i++) {
        float4 z4 = *(const float4*)&zs[r0 + i][k];
        acc[i] += z4.x * w0 + z4.y * w1 + z4.z * w2 + z4.w * w3;
      }
    }
  }
  float* Po = Pout + (size_t)s * DIM2 + d;
  #pragma unroll
  for (int i = 0; i < 8; i++) Po[(size_t)(r0 + i) * NSL * DIM2] = acc[i];
}

// ---------- head: final 12-way reduce + bias + lrelu ----------
__global__ void hl_reduce_kernel(const float* __restrict__ Pin, const void* __restrict__ bin_,
                                 float* __restrict__ out, long binoff,
                                 const int* __restrict__ flag) {
  int idx = blockIdx.x * 256 + threadIdx.x;  // 192 blocks x 256 = 49152
  int r = idx / DIM2, d = idx - r * DIM2;
  float acc = 0.0f;
  const float* Pr = Pin + (size_t)r * NSL * DIM2 + d;
  #pragma unroll
  for (int s = 0; s < NSL; s++) acc += Pr[(size_t)s * DIM2];
  float b;
  if (*flag) b = ((const float*)bin_ + binoff)[d];
  else       b = b2f(((const bf16*)bin_ + binoff)[d]);
  out[r * DIM2 + d] = lrelu(acc + b);
}

// ---------- final ----------
__global__ void final_kernel(const float* __restrict__ zin, const void* __restrict__ outW,
                             const void* __restrict__ outb, void* __restrict__ out,
                             const int* __restrict__ flag) {
  __shared__ float red[256];
  int r = blockIdx.x, t = threadIdx.x;
  int f32 = *flag;
  float acc = 0.0f;
  if (f32) {
    const float* W = (const float*)outW;
    for (int c = t; c < DIM2; c += 256) acc += zin[r * DIM2 + c] * W[c];
  } else {
    const bf16* W = (const bf16*)outW;
    for (int c = t; c < DIM2; c += 256) acc += zin[r * DIM2 + c] * b2f(W[c]);
  }
  red[t] = acc; __syncthreads();
  for (int s = 128; s > 0; s >>= 1) { if (t < s) red[t] += red[t + s]; __syncthreads(); }
  if (t == 0) {
    float ob;
    if (f32) ob = ((const float*)outb)[0]; else ob = b2f(((const bf16*)outb)[0]);
    float val = red[0] + ob;
    if (f32) ((float*)out)[r] = val;
    else     ((bf16*)out)[r] = __float2bfloat16(val);
  }
}

extern "C" void kernel_launch(void* const* d_in, const int* in_sizes, int n_in,
                              void* d_out, int out_size, void* d_ws, size_t ws_size,
                              hipStream_t stream) {
  const void* x      = d_in[0];
  const void* tag1_W = d_in[2];
  const void* tag1_b = d_in[3];
  const void* tag_W  = d_in[4];
  const void* tag_b  = d_in[5];
  const void* p1_W1  = d_in[6];
  const void* p1_b1  = d_in[7];
  const void* p1_W2  = d_in[8];
  const void* p1_b2  = d_in[9];
  const void* pf_W   = d_in[10];
  const void* pf_b   = d_in[11];
  const void* bn_g   = d_in[12];
  const void* bn_b   = d_in[13];
  const void* lin_W  = d_in[14];
  const void* lin_b  = d_in[15];
  const void* out_W  = d_in[16];
  const void* out_b  = d_in[17];

  // ---- workspace layout: total 10,485,776 floats ≈ 40 MB ----
  float* ws = (float*)d_ws;
  float* XF   = ws + 0;                 // 98304
  float* M16  = ws + 98304;             // 98304 (dead after proj3 C=6 -> reused as PP)
  float* M26  = ws + 196608;            // 98304
  float* Z    = ws + 294912;            // 49152
  float* ZB   = ws + 344064;            // 49152
  int*   FLAG = (int*)(ws + 409600);    // 16
  int*   NBRP = (int*)(ws + 409616);    // 49152 ints
  int*   NBRG = (int*)(ws + 458768);    // 1,638,400 ints -> ends 2,097,168
  float* S0   = ws + 2097168;           // 4 slots x 2,097,152 floats (8 MB each)
  float* S1   = ws + 4194320;           // S0+S1 contiguous -> 16 MB G region
  float* S2   = ws + 6291472;
  float* S3   = ws + 8388624;           // ends 10,485,776 floats
  float* PA   = S0;                     // head partials ping (589,824 floats)
  float* PB   = S1;                     // head partials pong
  float* PP   = M16;                    // pool partials (65536 floats)

  detect_kernel<<<1, 64, 0, stream>>>((const unsigned short*)x, FLAG);
  convert_kernel<<<384, 256, 0, stream>>>(x, XF, Bg * Nn * Fdim, FLAG);
  knn100_kernel<<<Bg * Nn / 4, 256, 0, stream>>>(XF, NBRG);
  knn3_x_kernel<<<Bg * Nn / 16, 256, 0, stream>>>(XF, NBRP);

  // ---- TAG branch ----
  gm6_kernel<<<Bg, 512, 0, stream>>>(XF, NBRG, M16);
  gm6_kernel<<<Bg, 512, 0, stream>>>(M16, NBRG, M26);
  proj3_kernel<<<2048, 128, 0, stream>>>(XF, M16, M26, tag1_W, tag1_b, S0, FLAG);
  pool1_kernel<<<256, 128, 0, stream>>>(S0, PP);
  pool2_kernel<<<Bg, 128, 0, stream>>>(PP, Z, 0, 128);

  gm128_kernel<<<Bg * Nn / 8, 256, 0, stream>>>(S0, NBRG, S1);
  gm128_kernel<<<Bg * Nn / 8, 256, 0, stream>>>(S1, NBRG, S2);
  proj3_big_kernel<<<512, 256, 0, stream>>>(S0, S1, S2, tag_W, tag_b, S3, 0, 0, FLAG);
  pool1_kernel<<<256, 128, 0, stream>>>(S3, PP);
  pool2_kernel<<<Bg, 128, 0, stream>>>(PP, Z, 256, 384);

  gm128_kernel<<<Bg * Nn / 8, 256, 0, stream>>>(S3, NBRG, S1);
  gm128_kernel<<<Bg * Nn / 8, 256, 0, stream>>>(S1, NBRG, S2);
  proj3_big_kernel<<<512, 256, 0, stream>>>(S3, S1, S2, tag_W, tag_b, S0,
                                            3L * 128 * 128, 128, FLAG);
  pool1_kernel<<<256, 128, 0, stream>>>(S0, PP);
  pool2_kernel<<<Bg, 128, 0, stream>>>(PP, Z, 512, 640);

  // ---- point branch ----
  proj_dual_kernel<<<2048, 128, 0, stream>>>(XF, p1_W1, S0, S1, FLAG);
  edge_mlp1_kernel<<<2048, 256, 0, stream>>>(S0, S1, NBRP, p1_W2, p1_b1, p1_b2, S2, FLAG);  // Y0=S2
  pool1_kernel<<<256, 128, 0, stream>>>(S2, PP);
  pool2_kernel<<<Bg, 128, 0, stream>>>(PP, Z, 768, 1152);

  for (int c = 0; c < Bg; c += GC16) {             // G=S0+S1 (U,V dead)
    gram_kernel<<<GC16 * 64, 256, 0, stream>>>(S2, S0, c);
    knn3_gram_kernel<<<GC16 * Nn / 16, 256, 0, stream>>>(S0, NBRP, c);
  }
  proj_dual_big_kernel<<<512, 256, 0, stream>>>(S2, pf_W, S0, S1, 0, FLAG);  // G dead
  edge_max_kernel<<<Bg * Nn, 128, 0, stream>>>(S0, S1, NBRP, pf_b, S3, 0, FLAG);  // Y1=S3
  pool1_kernel<<<256, 128, 0, stream>>>(S3, PP);
  pool2_kernel<<<Bg, 128, 0, stream>>>(PP, Z, 896, 1280);

  for (int c = 0; c < Bg; c += GC16) {             // G=S0+S1 (U,V dead)
    gram_kernel<<<GC16 * 64, 256, 0, stream>>>(S3, S0, c);
    knn3_gram_kernel<<<GC16 * Nn / 16, 256, 0, stream>>>(S0, NBRP, c);
  }
  proj_dual_big_kernel<<<512, 256, 0, stream>>>(S3, pf_W, S0, S1, 256L * 128, FLAG);  // G dead
  edge_max_kernel<<<Bg * Nn, 128, 0, stream>>>(S0, S1, NBRP, pf_b, S2, 128, FLAG);  // Y2=S2
  pool1_kernel<<<256, 128, 0, stream>>>(S2, PP);
  pool2_kernel<<<Bg, 128, 0, stream>>>(PP, Z, 1024, 1408);

  // ---- head: bn -> 5 x K-split linear (reduce fused into next stage) ----
  bn_kernel<<<6, 256, 0, stream>>>(Z, bn_g, bn_b, FLAG);
  hl_part_kernel<<<288, 256, 0, stream>>>(Z, nullptr, nullptr, lin_W, PA,
                                          0L * DIM2 * DIM2, 0L, 0, FLAG);
  hl_part_kernel<<<288, 256, 0, stream>>>(nullptr, PA, lin_b, lin_W, PB,
                                          1L * DIM2 * DIM2, 0L * DIM2, 1, FLAG);
  hl_part_kernel<<<288, 256, 0, stream>>>(nullptr, PB, lin_b, lin_W, PA,
                                          2L * DIM2 * DIM2, 1L * DIM2, 1, FLAG);
  hl_part_kernel<<<288, 256, 0, stream>>>(nullptr, PA, lin_b, lin_W, PB,
                                          3L * DIM2 * DIM2, 2L * DIM2, 1, FLAG);
  hl_part_kernel<<<288, 256, 0, stream>>>(nullptr, PB, lin_b, lin_W, PA,
                                          4L * DIM2 * DIM2, 3L * DIM2, 1, FLAG);
  hl_reduce_kernel<<<192, 256, 0, stream>>>(PA, lin_b, ZB, 4L * DIM2, FLAG);
  final_kernel<<<Bg, 256, 0, stream>>>(ZB, out_W, out_b, d_out, FLAG);
}

// Round 14
// 757.539 us; speedup vs baseline: 1.1343x; 1.1004x over previous
//
#include <hip/hip_runtime.h>
#include <hip/hip_bf16.h>

#define Bg 32
#define Nn 512
#define Fdim 6
#define Wd 128
#define KG 100
#define KP 3
#define DIM2 1536
#define GC16 16
#define NSL 12
#define KSL 128

typedef __hip_bfloat16 bf16;
typedef unsigned long long ull;

__device__ __forceinline__ float b2f(bf16 v) { return __bfloat162float(v); }
__device__ __forceinline__ float h2f(unsigned short h) { return __uint_as_float((unsigned)h << 16); }
__device__ __forceinline__ float lrelu(float v) { return v > 0.0f ? v : 0.01f * v; }

// ---------- dtype detection (f32=1 / bf16=0) ----------
__global__ void detect_kernel(const unsigned short* __restrict__ x, int* __restrict__ flag) {
  if (threadIdx.x == 0 && blockIdx.x == 0) {
    int big = 0;
    for (int i = 0; i < 512; i += 2) {
      unsigned short u = x[i];
      int e = (u >> 7) & 0xFF;
      if (e >= 140) big++;
    }
    *flag = (big > 20) ? 1 : 0;
  }
}

// ---------- convert x -> f32 ----------
__global__ void convert_kernel(const void* __restrict__ x, float* __restrict__ xf, int n,
                               const int* __restrict__ flag) {
  int i = blockIdx.x * 256 + threadIdx.x;
  if (i >= n) return;
  if (*flag) xf[i] = ((const float*)x)[i];
  else       xf[i] = b2f(((const bf16*)x)[i]);
}

// ---------- branchless sorted-3 insert ----------
__device__ __forceinline__ void ins3b(ull key, ull& k0, ull& k1, ull& k2) {
  ull M0 = k0 < key ? key : k0;  k0 = k0 < key ? k0 : key;
  ull M1 = k1 < M0 ? M0 : k1;    k1 = k1 < M0 ? k1 : M0;
  k2 = k2 < M1 ? k2 : M1;
}

// ---------- kNN k=100: one wave/row; ballot-popcount radix search ----------
__global__ void knn100_kernel(const float* __restrict__ xf, int* __restrict__ nbr) {
  __shared__ float xg[Nn * 7];
  __shared__ float sqv[Nn];
  int t = threadIdx.x; int w = t >> 6; int l = t & 63;
  int row0 = blockIdx.x * 4; int g = row0 >> 9;
  const float* xp = xf + g * (Nn * Fdim);
  for (int j = t; j < Nn; j += 256) {
    float s = 0.0f;
    #pragma unroll
    for (int c = 0; c < Fdim; c++) { float v = xp[j * Fdim + c]; xg[j * 7 + c] = v; s += v * v; }
    sqv[j] = s;
  }
  __syncthreads();
  int i = (row0 & 511) + w;
  float xi[Fdim];
  #pragma unroll
  for (int c = 0; c < Fdim; c++) xi[c] = xg[i * 7 + c];
  float sqi = sqv[i];
  unsigned m[8];
  #pragma unroll
  for (int ch = 0; ch < 8; ch++) {
    int j = ch * 64 + l;
    float dot = 0.0f;
    #pragma unroll
    for (int c = 0; c < Fdim; c++) dot += xi[c] * xg[j * 7 + c];
    float d = sqi + sqv[j] - 2.0f * dot;
    if (j == i) d += 1e10f;
    unsigned u = __float_as_uint(d);
    m[ch] = (u & 0x80000000u) ? ~u : (u | 0x80000000u);
  }
  unsigned T = 0u;
  for (int b = 31; b >= 0; b--) {
    unsigned mid = T | (1u << b);
    int c = 0;
    #pragma unroll
    for (int ch = 0; ch < 8; ch++) c += __popcll(__ballot(m[ch] < mid));
    if (c < KG) T = mid;
  }
  int* outp = nbr + ((size_t)(g * Nn + i)) * KG;
  ull lmask = (1ull << l) - 1ull;
  int base = 0;
  #pragma unroll
  for (int ch = 0; ch < 8; ch++) {
    bool less = m[ch] < T;
    ull bal = __ballot(less);
    if (less) outp[base + __popcll(bal & lmask)] = ch * 64 + l;
    base += __popcll(bal);
  }
  int need = KG - base;
  int eqb = 0;
  #pragma unroll
  for (int ch = 0; ch < 8; ch++) {
    bool eq = (m[ch] == T);
    ull bal = __ballot(eq);
    int gr = eqb + __popcll(bal & lmask);
    if (eq && gr < need) outp[base + gr] = ch * 64 + l;
    eqb += __popcll(bal);
  }
}

// ---------- kNN k=3 on coords: 16 lanes/row ----------
__global__ void knn3_x_kernel(const float* __restrict__ xf, int* __restrict__ nbr) {
  __shared__ float xg[Nn * 7];
  __shared__ float sqv[Nn];
  int t = threadIdx.x; int bid = blockIdx.x;
  int g = bid >> 5;
  const float* xp = xf + g * (Nn * Fdim);
  for (int j = t; j < Nn; j += 256) {
    float s = 0.0f;
    #pragma unroll
    for (int c = 0; c < Fdim; c++) { float v = xp[j * Fdim + c]; xg[j * 7 + c] = v; s += v * v; }
    sqv[j] = s;
  }
  __syncthreads();
  int lr = t >> 4; int sub = t & 15; int l = t & 63;
  int i = ((bid & 31) << 4) + lr;
  float xi[Fdim];
  #pragma unroll
  for (int c = 0; c < Fdim; c++) xi[c] = xg[i * 7 + c];
  float sqi = sqv[i];
  ull k0 = ~0ull, k1 = ~0ull, k2 = ~0ull;
  for (int jj = 0; jj < 32; jj++) {
    int s = (jj + l) & 31;
    int j = sub * 32 + s;
    float dot = 0.0f;
    #pragma unroll
    for (int c = 0; c < Fdim; c++) dot += xi[c] * xg[j * 7 + c];
    float d = sqi + sqv[j] - 2.0f * dot;
    if (j == i) d += 1e10f;
    unsigned u = __float_as_uint(d);
    unsigned m = (u & 0x80000000u) ? ~u : (u | 0x80000000u);
    ins3b(((ull)m << 32) | (unsigned)j, k0, k1, k2);
  }
  #pragma unroll
  for (int off = 1; off <= 8; off <<= 1) {
    ull b0 = __shfl_xor(k0, off, 64);
    ull b1 = __shfl_xor(k1, off, 64);
    ull b2 = __shfl_xor(k2, off, 64);
    ins3b(b0, k0, k1, k2); ins3b(b1, k0, k1, k2); ins3b(b2, k0, k1, k2);
  }
  if (sub == 0) {
    int row = g * Nn + i;
    nbr[row * 3 + 0] = (int)(k0 & 0xFFFFFFFFu);
    nbr[row * 3 + 1] = (int)(k1 & 0xFFFFFFFFu);
    nbr[row * 3 + 2] = (int)(k2 & 0xFFFFFFFFu);
  }
}

// ---------- kNN k=3 from chunked Gram ----------
__global__ void knn3_gram_kernel(const float* __restrict__ G, int* __restrict__ nbr, int g0) {
  __shared__ float sqv[Nn];
  int t = threadIdx.x; int bid = blockIdx.x;
  int gl = bid >> 5; int g = g0 + gl;
  const float* Gg = G + (size_t)gl * Nn * Nn;
  for (int j = t; j < Nn; j += 256) sqv[j] = Gg[(size_t)j * Nn + j];
  __syncthreads();
  int lr = t >> 4; int sub = t & 15; int l = t & 63;
  int i = ((bid & 31) << 4) + lr;
  float sqi = sqv[i];
  const float* Gr = Gg + (size_t)i * Nn;
  ull k0 = ~0ull, k1 = ~0ull, k2 = ~0ull;
  for (int jj = 0; jj < 32; jj++) {
    int s = (jj + l) & 31;
    int j = sub * 32 + s;
    float d = sqi + sqv[j] - 2.0f * Gr[j];
    if (j == i) d += 1e10f;
    unsigned u = __float_as_uint(d);
    unsigned m = (u & 0x80000000u) ? ~u : (u | 0x80000000u);
    ins3b(((ull)m << 32) | (unsigned)j, k0, k1, k2);
  }
  #pragma unroll
  for (int off = 1; off <= 8; off <<= 1) {
    ull b0 = __shfl_xor(k0, off, 64);
    ull b1 = __shfl_xor(k1, off, 64);
    ull b2 = __shfl_xor(k2, off, 64);
    ins3b(b0, k0, k1, k2); ins3b(b1, k0, k1, k2); ins3b(b2, k0, k1, k2);
  }
  if (sub == 0) {
    int row = g * Nn + i;
    nbr[row * 3 + 0] = (int)(k0 & 0xFFFFFFFFu);
    nbr[row * 3 + 1] = (int)(k1 & 0xFFFFFFFFu);
    nbr[row * 3 + 2] = (int)(k2 & 0xFFFFFFFFu);
  }
}

// ---------- neighbor-mean over 100, C=6 ----------
__global__ void gm6_kernel(const float* __restrict__ src, const int* __restrict__ nbr,
                           float* __restrict__ dst) {
  __shared__ float s[Nn * Fdim];
  int g = blockIdx.x; int t = threadIdx.x;  // 512
  const float* sp = src + g * (Nn * Fdim);
  for (int idx = t; idx < Nn * Fdim; idx += 512) s[idx] = sp[idx];
  __syncthreads();
  float acc[Fdim] = {0, 0, 0, 0, 0, 0};
  const int* nb = nbr + ((size_t)(g * Nn + t)) * KG;
  for (int k = 0; k < KG; k++) {
    int j = nb[k];
    #pragma unroll
    for (int c = 0; c < Fdim; c++) acc[c] += s[j * Fdim + c];
  }
  float* dp = dst + (size_t)(g * Nn + t) * Fdim;
  #pragma unroll
  for (int c = 0; c < Fdim; c++) dp[c] = acc[c] / 100.0f;
}

// ---------- neighbor-mean over 100, C=128: 8 rows/block, float4 gathers ----------
// r14: XCD-aware bijective swizzle (T1): blocks of one graph (64 consecutive)
// were round-robin'd across 8 XCDs -> each XCD re-fetched the graph's 256 KB
// src panel (FETCH 36.6 MB vs ~24.6 ideal). swz groups same-graph blocks onto
// one XCD. 2048 % 8 == 0 -> bijective.
__global__ void gm128_kernel(const float* __restrict__ src, const int* __restrict__ nbr,
                             float* __restrict__ dst) {
  __shared__ int ids[8][KG];
  int t = threadIdx.x;  // 256
  int bid = blockIdx.x;
  int swz = (bid & 7) * 256 + (bid >> 3);
  int row0 = swz * 8; int g = row0 >> 9;
  for (int idx = t; idx < 8 * KG; idx += 256) {
    int r = idx / KG, k = idx - r * KG;
    ids[r][k] = nbr[(size_t)(row0 + r) * KG + k];
  }
  __syncthreads();
  int lane = t & 31, r = t >> 5;  // r in 0..7
  const float4* sp = (const float4*)(src + (size_t)g * Nn * Wd);
  float ax = 0.0f, ay = 0.0f, az = 0.0f, aw = 0.0f;
  #pragma unroll 5
  for (int k = 0; k < KG; k++) {
    float4 v = sp[ids[r][k] * 32 + lane];
    ax += v.x; ay += v.y; az += v.z; aw += v.w;
  }
  float4 o = make_float4(ax / 100.0f, ay / 100.0f, az / 100.0f, aw / 100.0f);
  ((float4*)(dst + (size_t)(row0 + r) * Wd))[lane] = o;
}

// ---------- proj3 small (C=6 only; proven r10 path) ----------
__global__ void proj3_kernel(const float* __restrict__ in0, const float* __restrict__ in1,
                             const float* __restrict__ in2, const void* __restrict__ Wt_,
                             const void* __restrict__ bt_, float* __restrict__ out,
                             const int* __restrict__ flag) {
  __shared__ float s0[48], s1[48], s2[48];
  int t = threadIdx.x;  // 128
  int node0 = blockIdx.x * 8;
  int f32 = *flag;
  float acc[8] = {0, 0, 0, 0, 0, 0, 0, 0};
  float bd;
  if (t < 48) {
    s0[t] = in0[(size_t)node0 * 6 + t];
    s1[t] = in1[(size_t)node0 * 6 + t];
    s2[t] = in2[(size_t)node0 * 6 + t];
  }
  __syncthreads();
  if (f32) {
    const float* W = (const float*)Wt_;
    for (int c = 0; c < 6; c++) {
      float w0 = W[c * 128 + t], w1 = W[(6 + c) * 128 + t], w2 = W[(12 + c) * 128 + t];
      #pragma unroll
      for (int n = 0; n < 8; n++)
        acc[n] += s0[n * 6 + c] * w0 + s1[n * 6 + c] * w1 + s2[n * 6 + c] * w2;
    }
    bd = ((const float*)bt_)[t];
  } else {
    const bf16* W = (const bf16*)Wt_;
    for (int c = 0; c < 6; c++) {
      float w0 = b2f(W[c * 128 + t]), w1 = b2f(W[(6 + c) * 128 + t]), w2 = b2f(W[(12 + c) * 128 + t]);
      #pragma unroll
      for (int n = 0; n < 8; n++)
        acc[n] += s0[n * 6 + c] * w0 + s1[n * 6 + c] * w1 + s2[n * 6 + c] * w2;
    }
    bd = b2f(((const bf16*)bt_)[t]);
  }
  #pragma unroll
  for (int n = 0; n < 8; n++)
    out[(size_t)(node0 + n) * 128 + t] = lrelu(acc[n] + bd);
}

// ---------- proj3 big (C=128): chunk-staged W in LDS (64 rows, single-buffered) ----------
__global__ void proj3_big_kernel(const float* __restrict__ in0, const float* __restrict__ in1,
                                 const float* __restrict__ in2, const void* __restrict__ Wt_,
                                 const void* __restrict__ bt_, float* __restrict__ out,
                                 long Woff, long boff, const int* __restrict__ flag) {
  __shared__ __align__(16) float sa[3][32 * 128];  // 48 KB
  __shared__ __align__(16) float Wc[64 * 128];     // 32 KB chunk
  int t = threadIdx.x;  // 256
  int node0 = blockIdx.x * 32;
  int f32 = *flag;
  // ---- stage inputs ----
  {
    const float4* q0 = (const float4*)(in0 + (size_t)node0 * 128);
    const float4* q1 = (const float4*)(in1 + (size_t)node0 * 128);
    const float4* q2 = (const float4*)(in2 + (size_t)node0 * 128);
    float4* s0 = (float4*)sa[0]; float4* s1 = (float4*)sa[1]; float4* s2 = (float4*)sa[2];
    #pragma unroll
    for (int it = 0; it < 4; it++) {
      s0[t + it * 256] = q0[t + it * 256];
      s1[t + it * 256] = q1[t + it * 256];
      s2[t + it * 256] = q2[t + it * 256];
    }
  }
  int tx = t & 31, ty = t >> 5;
  int col0 = tx * 4, n0 = ty * 4;
  float acc[4][4];
  #pragma unroll
  for (int n = 0; n < 4; n++)
    #pragma unroll
    for (int j = 0; j < 4; j++) acc[n][j] = 0.0f;
  for (int half = 0; half < 6; half++) {   // a = half>>1, 64-row half h = half&1
    int a = half >> 1, h = half & 1;
    {
      float4* Wl = (float4*)Wc;
      if (f32) {
        const float4* Wg = (const float4*)((const float*)Wt_ + Woff
                                           + (size_t)a * 16384 + (size_t)h * 8192);
        #pragma unroll
        for (int i = 0; i < 8; i++) Wl[t + i * 256] = Wg[t + i * 256];
      } else {
        const ushort4* Wg = (const ushort4*)((const unsigned short*)Wt_ + Woff
                                             + (size_t)a * 16384 + (size_t)h * 8192);
        #pragma unroll
        for (int i = 0; i < 8; i++) {
          ushort4 hh = Wg[t + i * 256];
          Wl[t + i * 256] = make_float4(h2f(hh.x), h2f(hh.y), h2f(hh.z), h2f(hh.w));
        }
      }
    }
    __syncthreads();   // chunk (and, on half=0, inputs) visible
    const float* sp = sa[a];
    int cbase = h * 64;
    #pragma unroll 4
    for (int cc0 = 0; cc0 < 64; cc0 += 4) {
      float wv[4][4];
      #pragma unroll
      for (int cc = 0; cc < 4; cc++) {
        float4 w4 = *(const float4*)&Wc[(cc0 + cc) * 128 + col0];
        wv[cc][0] = w4.x; wv[cc][1] = w4.y; wv[cc][2] = w4.z; wv[cc][3] = w4.w;
      }
      int c0 = cbase + cc0;
      #pragma unroll
      for (int n = 0; n < 4; n++) {
        float4 av = *(const float4*)&sp[(n0 + n) * 128 + c0];
        #pragma unroll
        for (int j = 0; j < 4; j++)
          acc[n][j] += av.x * wv[0][j] + av.y * wv[1][j] + av.z * wv[2][j] + av.w * wv[3][j];
      }
    }
    __syncthreads();   // protect Wc before next stage
  }
  float bdv[4];
  if (f32) {
    const float* bt = (const float*)bt_ + boff;
    #pragma unroll
    for (int j = 0; j < 4; j++) bdv[j] = bt[col0 + j];
  } else {
    const bf16* bt = (const bf16*)bt_ + boff;
    #pragma unroll
    for (int j = 0; j < 4; j++) bdv[j] = b2f(bt[col0 + j]);
  }
  #pragma unroll
  for (int n = 0; n < 4; n++) {
    float4 ov;
    ov.x = lrelu(acc[n][0] + bdv[0]); ov.y = lrelu(acc[n][1] + bdv[1]);
    ov.z = lrelu(acc[n][2] + bdv[2]); ov.w = lrelu(acc[n][3] + bdv[3]);
    *(float4*)&out[(size_t)(node0 + n0 + n) * 128 + col0] = ov;
  }
}

// ---------- proj_dual small (C=6 only; proven r10 path) ----------
__global__ void proj_dual_kernel(const float* __restrict__ in, const void* __restrict__ Wt_,
                                 float* __restrict__ u, float* __restrict__ v,
                                 const int* __restrict__ flag) {
  __shared__ float s0[48];
  int t = threadIdx.x; int node0 = blockIdx.x * 8;
  int f32 = *flag;
  float au[8] = {0, 0, 0, 0, 0, 0, 0, 0};
  float av[8] = {0, 0, 0, 0, 0, 0, 0, 0};
  if (t < 48) s0[t] = in[(size_t)node0 * 6 + t];
  __syncthreads();
  if (f32) {
    const float* W = (const float*)Wt_;
    for (int c = 0; c < 6; c++) {
      float wa = W[c * 128 + t], wb = W[(6 + c) * 128 + t];
      #pragma unroll
      for (int n = 0; n < 8; n++) { float x = s0[n * 6 + c]; au[n] += x * wa; av[n] += x * wb; }
    }
  } else {
    const bf16* W = (const bf16*)Wt_;
    for (int c = 0; c < 6; c++) {
      float wa = b2f(W[c * 128 + t]), wb = b2f(W[(6 + c) * 128 + t]);
      #pragma unroll
      for (int n = 0; n < 8; n++) { float x = s0[n * 6 + c]; au[n] += x * wa; av[n] += x * wb; }
    }
  }
  #pragma unroll
  for (int n = 0; n < 8; n++) {
    u[(size_t)(node0 + n) * 128 + t] = au[n];
    v[(size_t)(node0 + n) * 128 + t] = av[n];
  }
}

// ---------- proj_dual big (C=128): chunk-staged W in LDS (4 x 64-row chunks) ----------
__global__ void proj_dual_big_kernel(const float* __restrict__ in, const void* __restrict__ Wt_,
                                     float* __restrict__ u, float* __restrict__ v,
                                     long Woff, const int* __restrict__ flag) {
  __shared__ __align__(16) float sa[32 * 128];     // 16 KB
  __shared__ __align__(16) float Wc[64 * 128];     // 32 KB chunk
  int t = threadIdx.x;  // 256
  int node0 = blockIdx.x * 32;
  int f32 = *flag;
  {
    const float4* qp = (const float4*)(in + (size_t)node0 * 128);
    float4* s0 = (float4*)sa;
    #pragma unroll
    for (int it = 0; it < 4; it++) s0[t + it * 256] = qp[t + it * 256];
  }
  int tx = t & 31, ty = t >> 5;
  int col0 = tx * 4, n0 = ty * 4;
  float accu[4][4], accv[4][4];
  #pragma unroll
  for (int n = 0; n < 4; n++)
    #pragma unroll
    for (int j = 0; j < 4; j++) { accu[n][j] = 0.0f; accv[n][j] = 0.0f; }
  for (int q = 0; q < 4; q++) {
    {
      float4* Wl = (float4*)Wc;
      if (f32) {
        const float4* Wg = (const float4*)((const float*)Wt_ + Woff + (size_t)q * 8192);
        #pragma unroll
        for (int i = 0; i < 8; i++) Wl[t + i * 256] = Wg[t + i * 256];
      } else {
        const ushort4* Wg = (const ushort4*)((const unsigned short*)Wt_ + Woff
                                             + (size_t)q * 8192);
        #pragma unroll
        for (int i = 0; i < 8; i++) {
          ushort4 hh = Wg[t + i * 256];
          Wl[t + i * 256] = make_float4(h2f(hh.x), h2f(hh.y), h2f(hh.z), h2f(hh.w));
        }
      }
    }
    __syncthreads();
    int cbase = (q & 1) * 64;
    if (q < 2) {
      #pragma unroll 4
      for (int cc0 = 0; cc0 < 64; cc0 += 4) {
        float wv[4][4];
        #pragma unroll
        for (int cc = 0; cc < 4; cc++) {
          float4 w4 = *(const float4*)&Wc[(cc0 + cc) * 128 + col0];
          wv[cc][0] = w4.x; wv[cc][1] = w4.y; wv[cc][2] = w4.z; wv[cc][3] = w4.w;
        }
        int c0 = cbase + cc0;
        #pragma unroll
        for (int n = 0; n < 4; n++) {
          float4 av = *(const float4*)&sa[(n0 + n) * 128 + c0];
          #pragma unroll
          for (int j = 0; j < 4; j++)
            accu[n][j] += av.x * wv[0][j] + av.y * wv[1][j] + av.z * wv[2][j] + av.w * wv[3][j];
        }
      }
    } else {
      #pragma unroll 4
      for (int cc0 = 0; cc0 < 64; cc0 += 4) {
        float wv[4][4];
        #pragma unroll
        for (int cc = 0; cc < 4; cc++) {
          float4 w4 = *(const float4*)&Wc[(cc0 + cc) * 128 + col0];
          wv[cc][0] = w4.x; wv[cc][1] = w4.y; wv[cc][2] = w4.z; wv[cc][3] = w4.w;
        }
        int c0 = cbase + cc0;
        #pragma unroll
        for (int n = 0; n < 4; n++) {
          float4 av = *(const float4*)&sa[(n0 + n) * 128 + c0];
          #pragma unroll
          for (int j = 0; j < 4; j++)
            accv[n][j] += av.x * wv[0][j] + av.y * wv[1][j] + av.z * wv[2][j] + av.w * wv[3][j];
        }
      }
    }
    __syncthreads();
  }
  #pragma unroll
  for (int n = 0; n < 4; n++) {
    *(float4*)&u[(size_t)(node0 + n0 + n) * 128 + col0] = *(float4*)accu[n];
    *(float4*)&v[(size_t)(node0 + n0 + n) * 128 + col0] = *(float4*)accv[n];
  }
}

// ---------- edgeconv1: half-W LDS staging (2 x 32 KB), single-buffered ----------
// r11 post-mortem: 6x8/32-node tile arc (r9-r11) all landed >=51 us vs this
// variant's ~43-47 us -- occupancy/latency dominates, not LDS reads. PARKED.
__global__ void edge_mlp1_kernel(const float* __restrict__ u, const float* __restrict__ v,
                                 const int* __restrict__ nbrp, const void* __restrict__ W2_,
                                 const void* __restrict__ b1_, const void* __restrict__ b2_,
                                 float* __restrict__ y, const int* __restrict__ flag) {
  __shared__ __align__(16) float Ws[64 * 128];  // 32 KB (one half of W)
  __shared__ __align__(16) float tl[24][128];   // 12 KB
  int t = threadIdx.x;  // 256
  int node0 = blockIdx.x * 8; int g = node0 >> 9;
  int f32 = *flag;
  // ---- stage W half 0 (K-rows 0..63) ----
  if (f32) {
    const float4* Wg = (const float4*)W2_;
    float4* Wl = (float4*)Ws;
    #pragma unroll
    for (int i = 0; i < 8; i++) Wl[t + i * 256] = Wg[t + i * 256];
  } else {
    const ushort4* Wg = (const ushort4*)W2_;
    float4* Wl = (float4*)Ws;
    #pragma unroll
    for (int i = 0; i < 8; i++) {
      ushort4 h = Wg[t + i * 256];
      Wl[t + i * 256] = make_float4(h2f(h.x), h2f(h.y), h2f(h.z), h2f(h.w));
    }
  }
  // ---- phase 1: group n = t>>5 builds tl rows 3n..3n+2 via float4 ----
  {
    int lane = t & 31, n = t >> 5;
    int row = node0 + n;
    float4 ui = ((const float4*)(u + (size_t)row * 128))[lane];
    float4 vi = ((const float4*)(v + (size_t)row * 128))[lane];
    float4 b1v;
    if (f32) b1v = ((const float4*)b1_)[lane];
    else {
      ushort4 h = ((const ushort4*)b1_)[lane];
      b1v = make_float4(h2f(h.x), h2f(h.y), h2f(h.z), h2f(h.w));
    }
    float4 base = make_float4(ui.x - vi.x + b1v.x, ui.y - vi.y + b1v.y,
                              ui.z - vi.z + b1v.z, ui.w - vi.w + b1v.w);
    #pragma unroll
    for (int k = 0; k < 3; k++) {
      int j = nbrp[row * 3 + k];
      float4 vj = ((const float4*)(v + (size_t)(g * Nn + j) * 128))[lane];
      float4 tv;
      tv.x = lrelu(base.x + vj.x); tv.y = lrelu(base.y + vj.y);
      tv.z = lrelu(base.z + vj.z); tv.w = lrelu(base.w + vj.w);
      *(float4*)&tl[n * 3 + k][lane * 4] = tv;
    }
  }
  __syncthreads();
  int tx = t & 31, ty = t >> 5;
  int col0 = tx * 4;
  float acc[3][4];
  #pragma unroll
  for (int k = 0; k < 3; k++)
    #pragma unroll
    for (int j = 0; j < 4; j++) acc[k][j] = 0.0f;
  // ---- compute half 0 (K = 0..63) ----
  #pragma unroll 4
  for (int cc0 = 0; cc0 < 64; cc0 += 4) {
    float wv[4][4];
    #pragma unroll
    for (int cc = 0; cc < 4; cc++) {
      float4 w4 = *(const float4*)&Ws[(cc0 + cc) * 128 + col0];
      wv[cc][0] = w4.x; wv[cc][1] = w4.y; wv[cc][2] = w4.z; wv[cc][3] = w4.w;
    }
    #pragma unroll
    for (int k = 0; k < 3; k++) {
      float4 av = *(const float4*)&tl[ty * 3 + k][cc0];
      #pragma unroll
      for (int j = 0; j < 4; j++)
        acc[k][j] += av.x * wv[0][j] + av.y * wv[1][j] + av.z * wv[2][j] + av.w * wv[3][j];
    }
  }
  __syncthreads();
  // ---- stage W half 1 (K-rows 64..127) ----
  if (f32) {
    const float4* Wg = (const float4*)W2_ + 2048;
    float4* Wl = (float4*)Ws;
    #pragma unroll
    for (int i = 0; i < 8; i++) Wl[t + i * 256] = Wg[t + i * 256];
  } else {
    const ushort4* Wg = (const ushort4*)W2_ + 2048;
    float4* Wl = (float4*)Ws;
    #pragma unroll
    for (int i = 0; i < 8; i++) {
      ushort4 h = Wg[t + i * 256];
      Wl[t + i * 256] = make_float4(h2f(h.x), h2f(h.y), h2f(h.z), h2f(h.w));
    }
  }
  __syncthreads();
  // ---- compute half 1 (K = 64..127) ----
  #pragma unroll 4
  for (int cc0 = 0; cc0 < 64; cc0 += 4) {
    float wv[4][4];
    #pragma unroll
    for (int cc = 0; cc < 4; cc++) {
      float4 w4 = *(const float4*)&Ws[(cc0 + cc) * 128 + col0];
      wv[cc][0] = w4.x; wv[cc][1] = w4.y; wv[cc][2] = w4.z; wv[cc][3] = w4.w;
    }
    #pragma unroll
    for (int k = 0; k < 3; k++) {
      float4 av = *(const float4*)&tl[ty * 3 + k][64 + cc0];
      #pragma unroll
      for (int j = 0; j < 4; j++)
        acc[k][j] += av.x * wv[0][j] + av.y * wv[1][j] + av.z * wv[2][j] + av.w * wv[3][j];
    }
  }
  float b2d[4];
  if (f32) {
    const float* b2p = (const float*)b2_;
    #pragma unroll
    for (int j = 0; j < 4; j++) b2d[j] = b2p[col0 + j];
  } else {
    const bf16* b2p = (const bf16*)b2_;
    #pragma unroll
    for (int j = 0; j < 4; j++) b2d[j] = b2f(b2p[col0 + j]);
  }
  float4 ov;
  {
    float m0 = lrelu(acc[0][0] + b2d[0]);
    m0 = fmaxf(m0, lrelu(acc[1][0] + b2d[0]));
    ov.x = fmaxf(m0, lrelu(acc[2][0] + b2d[0]));
    float m1 = lrelu(acc[0][1] + b2d[1]);
    m1 = fmaxf(m1, lrelu(acc[1][1] + b2d[1]));
    ov.y = fmaxf(m1, lrelu(acc[2][1] + b2d[1]));
    float m2 = lrelu(acc[0][2] + b2d[2]);
    m2 = fmaxf(m2, lrelu(acc[1][2] + b2d[2]));
    ov.z = fmaxf(m2, lrelu(acc[2][2] + b2d[2]));
    float m3 = lrelu(acc[0][3] + b2d[3]);
    m3 = fmaxf(m3, lrelu(acc[1][3] + b2d[3]));
    ov.w = fmaxf(m3, lrelu(acc[2][3] + b2d[3]));
  }
  *(float4*)&y[(size_t)(node0 + ty) * 128 + col0] = ov;
}

// ---------- edgeconv2/3 ----------
__global__ void edge_max_kernel(const float* __restrict__ u, const float* __restrict__ v,
                                const int* __restrict__ nbrp, const void* __restrict__ bias_,
                                float* __restrict__ y, long boff, const int* __restrict__ flag) {
  int row = blockIdx.x; int g = row >> 9; int t = threadIdx.x;  // 128
  float ui = u[(size_t)row * 128 + t], vi = v[(size_t)row * 128 + t];
  float bd;
  if (*flag) bd = ((const float*)bias_ + boff)[t]; else bd = b2f(((const bf16*)bias_ + boff)[t]);
  float m = -3.4e38f;
  #pragma unroll
  for (int k = 0; k < 3; k++) {
    int j = nbrp[row * 3 + k];
    m = fmaxf(m, lrelu(ui - vi + v[(size_t)(g * Nn + j) * 128 + t] + bd));
  }
  y[(size_t)row * 128 + t] = m;
}

// ---------- chunked Gram matrix: transposed LDS tiles + float4 reads ----------
__global__ void gram_kernel(const float* __restrict__ y, float* __restrict__ G, int g0) {
  __shared__ float At[16][68], Bt[16][68];
  int bid = blockIdx.x;
  int gl = bid >> 6; int tt = bid & 63; int ti = tt >> 3; int tj = tt & 7;
  int g = g0 + gl;
  int t = threadIdx.x; int tx = t & 15, ty = t >> 4;
  const float* Yg = y + (size_t)g * Nn * Wd;
  float* Gg = G + (size_t)gl * Nn * Nn;
  int sr = t >> 2, sq = (t & 3) * 4;   // staging: row 0..63, col-quad
  float c[4][4];
  #pragma unroll
  for (int p = 0; p < 4; p++)
    #pragma unroll
    for (int q = 0; q < 4; q++) c[p][q] = 0.0f;
  for (int k0 = 0; k0 < 128; k0 += 16) {
    {
      float4 a4 = *(const float4*)&Yg[(ti * 64 + sr) * 128 + k0 + sq];
      float4 b4 = *(const float4*)&Yg[(tj * 64 + sr) * 128 + k0 + sq];
      At[sq + 0][sr] = a4.x; At[sq + 1][sr] = a4.y; At[sq + 2][sr] = a4.z; At[sq + 3][sr] = a4.w;
      Bt[sq + 0][sr] = b4.x; Bt[sq + 1][sr] = b4.y; Bt[sq + 2][sr] = b4.z; Bt[sq + 3][sr] = b4.w;
    }
    __syncthreads();
    #pragma unroll 4
    for (int kk = 0; kk < 16; kk++) {
      float4 a4 = *(const float4*)&At[kk][ty * 4];
      float4 b4 = *(const float4*)&Bt[kk][tx * 4];
      float a[4] = {a4.x, a4.y, a4.z, a4.w};
      float bb[4] = {b4.x, b4.y, b4.z, b4.w};
      #pragma unroll
      for (int p = 0; p < 4; p++)
        #pragma unroll
        for (int q = 0; q < 4; q++) c[p][q] += a[p] * bb[q];
    }
    __syncthreads();
  }
  #pragma unroll
  for (int p = 0; p < 4; p++)
    #pragma unroll
    for (int q = 0; q < 4; q++)
      Gg[(size_t)(ti * 64 + ty * 4 + p) * Nn + tj * 64 + tx * 4 + q] = c[p][q];
}

// ---------- fused mean+max pool: one launch per site (was pool1+pool2) ----------
// r14: pool1(256blk)+pool2(32blk) were two serial latency-bound launches + a
// PP round-trip. Fused: 128 blocks (graph x 4 col-groups), 8 rowgroups/col,
// 2 KB LDS tree. Same read volume, one launch, no PP traffic.
__global__ void pool_kernel(const float* __restrict__ h, float* __restrict__ z,
                            int meanoff, int maxoff) {
  __shared__ float ssum[8][32], smax[8][32];
  int b = blockIdx.x;            // 128: g*4 + cg
  int g = b >> 2, cg = b & 3;
  int t = threadIdx.x;           // 256
  int cl = t & 31, r8 = t >> 5;  // col-in-group, rowgroup 0..7
  int col = cg * 32 + cl;
  const float* hg = h + (size_t)g * Nn * Wd + (size_t)r8 * 64 * Wd + col;
  float s = 0.0f, m = -3.4e38f;
  #pragma unroll 4
  for (int n = 0; n < 64; n++) {
    float vv = hg[n * 128];
    s += vv; m = fmaxf(m, vv);
  }
  ssum[r8][cl] = s; smax[r8][cl] = m;
  __syncthreads();
  if (r8 == 0) {
    #pragma unroll
    for (int q = 1; q < 8; q++) {
      s += ssum[q][cl];
      m = fmaxf(m, smax[q][cl]);
    }
    z[g * DIM2 + meanoff + col] = s / 512.0f;
    z[g * DIM2 + maxoff + col] = m;
  }
}

// ---------- BatchNorm1d (batch stats), in place ----------
__global__ void bn_kernel(float* __restrict__ z, const void* __restrict__ gamma,
                          const void* __restrict__ beta, const int* __restrict__ flag) {
  int c = blockIdx.x * 256 + threadIdx.x;
  if (c >= DIM2) return;
  float s = 0.0f;
  for (int r = 0; r < Bg; r++) s += z[r * DIM2 + c];
  float mu = s / 32.0f;
  float v = 0.0f;
  for (int r = 0; r < Bg; r++) { float d = z[r * DIM2 + c] - mu; v += d * d; }
  float var = v / 32.0f;
  float gm, bt;
  if (*flag) { gm = ((const float*)gamma)[c]; bt = ((const float*)beta)[c]; }
  else       { gm = b2f(((const bf16*)gamma)[c]); bt = b2f(((const bf16*)beta)[c]); }
  float scale = gm / sqrtf(var + 1e-5f);
  for (int r = 0; r < Bg; r++) z[r * DIM2 + c] = (z[r * DIM2 + c] - mu) * scale + bt;
}

// ---------- head linear, K-split partial GEMM (no transpose) ----------
__global__ void hl_part_kernel(const float* __restrict__ zin, const float* __restrict__ Pin,
                               const void* __restrict__ bin_, const void* __restrict__ W_,
                               float* __restrict__ Pout, long Woff, long binoff, int mode,
                               const int* __restrict__ flag) {
  __shared__ __align__(16) float zs[32][KSL];  // 16 KB
  int t = threadIdx.x;  // 256
  int bd = blockIdx.x % 24, s = blockIdx.x / 24;
  int d0 = bd * 64, k0 = s * KSL;
  int f32 = *flag;
  if (mode == 0) {
    for (int idx = t; idx < 32 * KSL; idx += 256) {
      int r = idx >> 7, k = idx & 127;
      zs[r][k] = zin[r * DIM2 + k0 + k];
    }
  } else {
    // z[r][k] = lrelu(sum_s Pin[r][s][k0+k] + b[k0+k])
    for (int idx = t; idx < 32 * KSL / 4; idx += 256) {
      int r = idx >> 5, k4 = (idx & 31) * 4;
      float ax = 0.0f, ay = 0.0f, az = 0.0f, aw = 0.0f;
      const float* Pr = Pin + (size_t)r * NSL * DIM2 + k0 + k4;
      #pragma unroll
      for (int ss = 0; ss < NSL; ss++) {
        float4 p = *(const float4*)(Pr + (size_t)ss * DIM2);
        ax += p.x; ay += p.y; az += p.z; aw += p.w;
      }
      float b0, b1, b2, b3;
      if (f32) {
        const float* bp = (const float*)bin_ + binoff + k0 + k4;
        b0 = bp[0]; b1 = bp[1]; b2 = bp[2]; b3 = bp[3];
      } else {
        const bf16* bp = (const bf16*)bin_ + binoff + k0 + k4;
        b0 = b2f(bp[0]); b1 = b2f(bp[1]); b2 = b2f(bp[2]); b3 = b2f(bp[3]);
      }
      zs[r][k4 + 0] = lrelu(ax + b0);
      zs[r][k4 + 1] = lrelu(ay + b1);
      zs[r][k4 + 2] = lrelu(az + b2);
      zs[r][k4 + 3] = lrelu(aw + b3);
    }
  }
  __syncthreads();
  int lane = t & 63, rg = t >> 6;  // 64 cols per wave; 4 rowgroups of 8 rows
  int d = d0 + lane, r0 = rg * 8;
  float acc[8];
  #pragma unroll
  for (int i = 0; i < 8; i++) acc[i] = 0.0f;
  if (f32) {
    const float* W = (const float*)W_ + Woff;
    for (int k = 0; k < KSL; k += 4) {
      float w0 = W[(size_t)(k0 + k) * DIM2 + d];
      float w1 = W[(size_t)(k0 + k + 1) * DIM2 + d];
      float w2 = W[(size_t)(k0 + k + 2) * DIM2 + d];
      float w3 = W[(size_t)(k0 + k + 3) * DIM2 + d];
      #pragma unroll
      for (int i = 0; i < 8; i++) {
        float4 z4 = *(const float4*)&zs[r0 + i][k];
        acc[i] += z4.x * w0 + z4.y * w1 + z4.z * w2 + z4.w * w3;
      }
    }
  } else {
    const unsigned short* W = (const unsigned short*)W_ + Woff;
    for (int k = 0; k < KSL; k += 4) {
      float w0 = h2f(W[(size_t)(k0 + k) * DIM2 + d]);
      float w1 = h2f(W[(size_t)(k0 + k + 1) * DIM2 + d]);
      float w2 = h2f(W[(size_t)(k0 + k + 2) * DIM2 + d]);
      float w3 = h2f(W[(size_t)(k0 + k + 3) * DIM2 + d]);
      #pragma unroll
      for (int i = 0; i < 8; i++) {
        float4 z4 = *(const float4*)&zs[r0 + i][k];
        acc[i] += z4.x * w0 + z4.y * w1 + z4.z * w2 + z4.w * w3;
      }
    }
  }
  float* Po = Pout + (size_t)s * DIM2 + d;
  #pragma unroll
  for (int i = 0; i < 8; i++) Po[(size_t)(r0 + i) * NSL * DIM2] = acc[i];
}

// ---------- head: final 12-way reduce + bias + lrelu ----------
__global__ void hl_reduce_kernel(const float* __restrict__ Pin, const void* __restrict__ bin_,
                                 float* __restrict__ out, long binoff,
                                 const int* __restrict__ flag) {
  int idx = blockIdx.x * 256 + threadIdx.x;  // 192 blocks x 256 = 49152
  int r = idx / DIM2, d = idx - r * DIM2;
  float acc = 0.0f;
  const float* Pr = Pin + (size_t)r * NSL * DIM2 + d;
  #pragma unroll
  for (int s = 0; s < NSL; s++) acc += Pr[(size_t)s * DIM2];
  float b;
  if (*flag) b = ((const float*)bin_ + binoff)[d];
  else       b = b2f(((const bf16*)bin_ + binoff)[d]);
  out[r * DIM2 + d] = lrelu(acc + b);
}

// ---------- final ----------
__global__ void final_kernel(const float* __restrict__ zin, const void* __restrict__ outW,
                             const void* __restrict__ outb, void* __restrict__ out,
                             const int* __restrict__ flag) {
  __shared__ float red[256];
  int r = blockIdx.x, t = threadIdx.x;
  int f32 = *flag;
  float acc = 0.0f;
  if (f32) {
    const float* W = (const float*)outW;
    for (int c = t; c < DIM2; c += 256) acc += zin[r * DIM2 + c] * W[c];
  } else {
    const bf16* W = (const bf16*)outW;
    for (int c = t; c < DIM2; c += 256) acc += zin[r * DIM2 + c] * b2f(W[c]);
  }
  red[t] = acc; __syncthreads();
  for (int s = 128; s > 0; s >>= 1) { if (t < s) red[t] += red[t + s]; __syncthreads(); }
  if (t == 0) {
    float ob;
    if (f32) ob = ((const float*)outb)[0]; else ob = b2f(((const bf16*)outb)[0]);
    float val = red[0] + ob;
    if (f32) ((float*)out)[r] = val;
    else     ((bf16*)out)[r] = __float2bfloat16(val);
  }
}

extern "C" void kernel_launch(void* const* d_in, const int* in_sizes, int n_in,
                              void* d_out, int out_size, void* d_ws, size_t ws_size,
                              hipStream_t stream) {
  const void* x      = d_in[0];
  const void* tag1_W = d_in[2];
  const void* tag1_b = d_in[3];
  const void* tag_W  = d_in[4];
  const void* tag_b  = d_in[5];
  const void* p1_W1  = d_in[6];
  const void* p1_b1  = d_in[7];
  const void* p1_W2  = d_in[8];
  const void* p1_b2  = d_in[9];
  const void* pf_W   = d_in[10];
  const void* pf_b   = d_in[11];
  const void* bn_g   = d_in[12];
  const void* bn_b   = d_in[13];
  const void* lin_W  = d_in[14];
  const void* lin_b  = d_in[15];
  const void* out_W  = d_in[16];
  const void* out_b  = d_in[17];

  // ---- workspace layout: total 10,485,776 floats ≈ 40 MB ----
  float* ws = (float*)d_ws;
  float* XF   = ws + 0;                 // 98304
  float* M16  = ws + 98304;             // 98304
  float* M26  = ws + 196608;            // 98304
  float* Z    = ws + 294912;            // 49152
  float* ZB   = ws + 344064;            // 49152
  int*   FLAG = (int*)(ws + 409600);    // 16
  int*   NBRP = (int*)(ws + 409616);    // 49152 ints
  int*   NBRG = (int*)(ws + 458768);    // 1,638,400 ints -> ends 2,097,168
  float* S0   = ws + 2097168;           // 4 slots x 2,097,152 floats (8 MB each)
  float* S1   = ws + 4194320;           // S0+S1 contiguous -> 16 MB G region
  float* S2   = ws + 6291472;
  float* S3   = ws + 8388624;           // ends 10,485,776 floats
  float* PA   = S0;                     // head partials ping (589,824 floats)
  float* PB   = S1;                     // head partials pong

  detect_kernel<<<1, 64, 0, stream>>>((const unsigned short*)x, FLAG);
  convert_kernel<<<384, 256, 0, stream>>>(x, XF, Bg * Nn * Fdim, FLAG);
  knn100_kernel<<<Bg * Nn / 4, 256, 0, stream>>>(XF, NBRG);
  knn3_x_kernel<<<Bg * Nn / 16, 256, 0, stream>>>(XF, NBRP);

  // ---- TAG branch ----
  gm6_kernel<<<Bg, 512, 0, stream>>>(XF, NBRG, M16);
  gm6_kernel<<<Bg, 512, 0, stream>>>(M16, NBRG, M26);
  proj3_kernel<<<2048, 128, 0, stream>>>(XF, M16, M26, tag1_W, tag1_b, S0, FLAG);
  pool_kernel<<<128, 256, 0, stream>>>(S0, Z, 0, 128);

  gm128_kernel<<<Bg * Nn / 8, 256, 0, stream>>>(S0, NBRG, S1);
  gm128_kernel<<<Bg * Nn / 8, 256, 0, stream>>>(S1, NBRG, S2);
  proj3_big_kernel<<<512, 256, 0, stream>>>(S0, S1, S2, tag_W, tag_b, S3, 0, 0, FLAG);
  pool_kernel<<<128, 256, 0, stream>>>(S3, Z, 256, 384);

  gm128_kernel<<<Bg * Nn / 8, 256, 0, stream>>>(S3, NBRG, S1);
  gm128_kernel<<<Bg * Nn / 8, 256, 0, stream>>>(S1, NBRG, S2);
  proj3_big_kernel<<<512, 256, 0, stream>>>(S3, S1, S2, tag_W, tag_b, S0,
                                            3L * 128 * 128, 128, FLAG);
  pool_kernel<<<128, 256, 0, stream>>>(S0, Z, 512, 640);

  // ---- point branch ----
  proj_dual_kernel<<<2048, 128, 0, stream>>>(XF, p1_W1, S0, S1, FLAG);
  edge_mlp1_kernel<<<2048, 256, 0, stream>>>(S0, S1, NBRP, p1_W2, p1_b1, p1_b2, S2, FLAG);  // Y0=S2
  pool_kernel<<<128, 256, 0, stream>>>(S2, Z, 768, 1152);

  for (int c = 0; c < Bg; c += GC16) {             // G=S0+S1 (U,V dead)
    gram_kernel<<<GC16 * 64, 256, 0, stream>>>(S2, S0, c);
    knn3_gram_kernel<<<GC16 * Nn / 16, 256, 0, stream>>>(S0, NBRP, c);
  }
  proj_dual_big_kernel<<<512, 256, 0, stream>>>(S2, pf_W, S0, S1, 0, FLAG);  // G dead
  edge_max_kernel<<<Bg * Nn, 128, 0, stream>>>(S0, S1, NBRP, pf_b, S3, 0, FLAG);  // Y1=S3
  pool_kernel<<<128, 256, 0, stream>>>(S3, Z, 896, 1280);

  for (int c = 0; c < Bg; c += GC16) {             // G=S0+S1 (U,V dead)
    gram_kernel<<<GC16 * 64, 256, 0, stream>>>(S3, S0, c);
    knn3_gram_kernel<<<GC16 * Nn / 16, 256, 0, stream>>>(S0, NBRP, c);
  }
  proj_dual_big_kernel<<<512, 256, 0, stream>>>(S3, pf_W, S0, S1, 256L * 128, FLAG);  // G dead
  edge_max_kernel<<<Bg * Nn, 128, 0, stream>>>(S0, S1, NBRP, pf_b, S2, 128, FLAG);  // Y2=S2
  pool_kernel<<<128, 256, 0, stream>>>(S2, Z, 1024, 1408);

  // ---- head: bn -> 5 x K-split linear (reduce fused into next stage) ----
  bn_kernel<<<6, 256, 0, stream>>>(Z, bn_g, bn_b, FLAG);
  hl_part_kernel<<<288, 256, 0, stream>>>(Z, nullptr, nullptr, lin_W, PA,
                                          0L * DIM2 * DIM2, 0L, 0, FLAG);
  hl_part_kernel<<<288, 256, 0, stream>>>(nullptr, PA, lin_b, lin_W, PB,
                                          1L * DIM2 * DIM2, 0L * DIM2, 1, FLAG);
  hl_part_kernel<<<288, 256, 0, stream>>>(nullptr, PB, lin_b, lin_W, PA,
                                          2L * DIM2 * DIM2, 1L * DIM2, 1, FLAG);
  hl_part_kernel<<<288, 256, 0, stream>>>(nullptr, PA, lin_b, lin_W, PB,
                                          3L * DIM2 * DIM2, 2L * DIM2, 1, FLAG);
  hl_part_kernel<<<288, 256, 0, stream>>>(nullptr, PB, lin_b, lin_W, PA,
                                          4L * DIM2 * DIM2, 3L * DIM2, 1, FLAG);
  hl_reduce_kernel<<<192, 256, 0, stream>>>(PA, lin_b, ZB, 4L * DIM2, FLAG);
  final_kernel<<<Bg, 256, 0, stream>>>(ZB, out_W, out_b, d_out, FLAG);
}